// Round 1
// baseline (2331.722 us; speedup 1.0000x reference)
//
#include <hip/hip_runtime.h>

// Problem constants (L,B,E,H,R) = (2048, 2, 768, 12, 64)
#define LSEQ 2048
#define BATCH 2
#define EMB 768
#define NH 12
#define HD 64
#define RNK 64
#define E3 2304            // 3*EMB
#define LB (LSEQ*BATCH)    // 4096 rows, row index r = i*BATCH + b
#define JCH 128            // attention j-chunk

// ---------------------------------------------------------------------------
// Generic f32 tiled GEMM:  C = epilogue( A(M,K) @ W(N,K)^T )
// LDS is stored transposed [BK][BM+4] so per-thread fragment reads are
// contiguous (merge to ds_read_b128).  LORA adds a second K=64 pass with
// A-operand pre-scaled by ls (exactly  (T@U^T + ub)*ls  folded into acc).
// ---------------------------------------------------------------------------
#define GEMM_TILE_LOOP(PTRA, LDA, PTRB, LDB, KLEN, AMUL)                          \
  for (int k0 = 0; k0 < (KLEN); k0 += BK) {                                       \
    for (int idx = (int)threadIdx.x; idx < BM*4; idx += 256) {                    \
      int r = idx >> 2, cq = idx & 3;                                             \
      float4 t4 = *(const float4*)((PTRA) + (size_t)(row0+r)*(LDA) + k0 + cq*4);  \
      As[cq*4+0][r] = t4.x * (AMUL);                                              \
      As[cq*4+1][r] = t4.y * (AMUL);                                              \
      As[cq*4+2][r] = t4.z * (AMUL);                                              \
      As[cq*4+3][r] = t4.w * (AMUL);                                              \
    }                                                                             \
    for (int idx = (int)threadIdx.x; idx < BN*4; idx += 256) {                    \
      int r = idx >> 2, cq = idx & 3;                                             \
      float4 t4 = *(const float4*)((PTRB) + (size_t)(col0+r)*(LDB) + k0 + cq*4);  \
      Bs[cq*4+0][r] = t4.x;                                                       \
      Bs[cq*4+1][r] = t4.y;                                                       \
      Bs[cq*4+2][r] = t4.z;                                                       \
      Bs[cq*4+3][r] = t4.w;                                                       \
    }                                                                             \
    __syncthreads();                                                              \
    _Pragma("unroll")                                                             \
    for (int k = 0; k < BK; ++k) {                                                \
      float a[TM], bb[TN];                                                        \
      _Pragma("unroll")                                                           \
      for (int i = 0; i < TM; ++i) a[i] = As[k][ty*TM+i];                         \
      _Pragma("unroll")                                                           \
      for (int j = 0; j < TN; ++j) bb[j] = Bs[k][tx*TN+j];                        \
      _Pragma("unroll")                                                           \
      for (int i = 0; i < TM; ++i)                                                \
        _Pragma("unroll")                                                         \
        for (int j = 0; j < TN; ++j) acc[i][j] = fmaf(a[i], bb[j], acc[i][j]);    \
    }                                                                             \
    __syncthreads();                                                              \
  }

template<int BM, int BN, bool RELU, bool LORA, bool SSF, bool QSCALE>
__global__ __launch_bounds__(256) void gemm_fused(
    const float* __restrict__ A, const float* __restrict__ W,
    const float* __restrict__ bias,
    const float* __restrict__ scale, const float* __restrict__ shift,
    const float* __restrict__ Tm, const float* __restrict__ U,
    const float* __restrict__ ub, const float* __restrict__ ls,
    float* __restrict__ C, int M, int N, int K)
{
  (void)M;
  constexpr int BK = 16;
  constexpr int TM = BM / 16, TN = BN / 16;
  __shared__ float As[BK][BM+4];
  __shared__ float Bs[BK][BN+4];
  const int tx = (int)threadIdx.x & 15, ty = (int)threadIdx.x >> 4;
  const int row0 = blockIdx.x * BM, col0 = blockIdx.y * BN;

  float acc[TM][TN];
  #pragma unroll
  for (int i = 0; i < TM; ++i)
    #pragma unroll
    for (int j = 0; j < TN; ++j) acc[i][j] = 0.f;

  GEMM_TILE_LOOP(A, K, W, K, K, 1.0f)

  float lsv = 0.f;
  if constexpr (LORA) lsv = ls[0];

  // epilogue part 1:  (acc + bias) [*scale + shift] [+ ub*ls]
  #pragma unroll
  for (int i = 0; i < TM; ++i) {
    #pragma unroll
    for (int j = 0; j < TN; ++j) {
      const int c = col0 + tx*TN + j;
      float v = acc[i][j] + bias[c];
      if constexpr (SSF)  v = v*scale[c] + shift[c];
      if constexpr (LORA) v += ub[c]*lsv;
      acc[i][j] = v;
    }
  }

  if constexpr (LORA) {
    GEMM_TILE_LOOP(Tm, RNK, U, RNK, RNK, lsv)
  }

  #pragma unroll
  for (int i = 0; i < TM; ++i) {
    const int r = row0 + ty*TM + i;
    #pragma unroll
    for (int j = 0; j < TN; ++j) {
      const int c = col0 + tx*TN + j;
      float v = acc[i][j];
      if constexpr (QSCALE) { if (c < EMB) v *= 0.125f; }  // hd^-0.5
      if constexpr (RELU)   v = fmaxf(v, 0.f);
      C[(size_t)r*N + c] = v;
    }
  }
}

// ---------------------------------------------------------------------------
// Attention: one block per (b, 16-row i-tile), loops over all 12 heads.
//  pass1: QK^T scores (saved in regs) + per-thread online (m,l), then
//         width-32 shfl butterfly (all 32 j-threads of a row are in one wave).
//  pass2: p = exp(s-m)/l -> pch LDS; attnW (mean over h) via exclusive global
//         RMW (h==0 writes); PV accumulated with float4 v fragments.
// ---------------------------------------------------------------------------
__global__ __launch_bounds__(512) void attn_fused(
    const float* __restrict__ qkv, float* __restrict__ attnO,
    float* __restrict__ attnW)
{
  const int i0 = blockIdx.x * 16;
  const int b  = blockIdx.y;
  const int t  = (int)threadIdx.x;

  __shared__ float qs[16][HD];
  __shared__ float ks[JCH][HD+4];
  __shared__ float vs[JCH][HD+4];
  __shared__ float pch[16][JCH];
  __shared__ float pvred[16][HD+4];

  const int irow = t >> 5;          // 0..15 : score row
  const int jt   = t & 31;          // 0..31 : j-thread within row
  const int dq   = t & 15;          // PV: d quad
  const int ii   = (t >> 4) & 15;   // PV: row
  const int jh   = t >> 8;          // PV: j half (0/1)

  for (int h = 0; h < NH; ++h) {
    __syncthreads();
    for (int idx = t; idx < 16*HD; idx += 512) {
      int i = idx >> 6, d = idx & 63;
      qs[i][d] = qkv[(size_t)((i0+i)*BATCH + b)*E3 + h*HD + d];
    }
    __syncthreads();
    float4 qr[16];
    #pragma unroll
    for (int q = 0; q < 16; ++q) qr[q] = *(const float4*)&qs[irow][q*4];

    float m = -1e30f, l = 0.f;
    float ssave[64];                 // statically indexed (loops fully unrolled)

    // ---- pass 1: scores + online softmax stats -----------------------------
    #pragma unroll
    for (int c = 0; c < LSEQ/JCH; ++c) {
      __syncthreads();
      for (int idx = t; idx < JCH*(HD/4); idx += 512) {
        int r = idx >> 4, cq = idx & 15;
        *(float4*)&ks[r][cq*4] =
          *(const float4*)(qkv + (size_t)((c*JCH + r)*BATCH + b)*E3 + EMB + h*HD + cq*4);
      }
      __syncthreads();
      #pragma unroll
      for (int sub = 0; sub < JCH/32; ++sub) {
        const int jj = jt + sub*32;
        float s = 0.f;
        #pragma unroll
        for (int q = 0; q < 16; ++q) {
          float4 kk = *(const float4*)&ks[jj][q*4];
          s = fmaf(qr[q].x, kk.x, s);
          s = fmaf(qr[q].y, kk.y, s);
          s = fmaf(qr[q].z, kk.z, s);
          s = fmaf(qr[q].w, kk.w, s);
        }
        ssave[c*4 + sub] = s;
        float mn = fmaxf(m, s);
        l = l*__expf(m - mn) + __expf(s - mn);
        m = mn;
      }
    }
    // butterfly merge across the 32 j-threads of this row (single wave)
    #pragma unroll
    for (int off = 1; off < 32; off <<= 1) {
      float om = __shfl_xor(m, off);
      float ol = __shfl_xor(l, off);
      float mn = fmaxf(m, om);
      l = l*__expf(m - mn) + ol*__expf(om - mn);
      m = mn;
    }
    const float linv = 1.f / l;

    // ---- pass 2: probabilities, attn_weights, PV ---------------------------
    float4 acc4 = make_float4(0.f, 0.f, 0.f, 0.f);
    #pragma unroll
    for (int c = 0; c < LSEQ/JCH; ++c) {
      __syncthreads();
      for (int idx = t; idx < JCH*(HD/4); idx += 512) {
        int r = idx >> 4, cq = idx & 15;
        *(float4*)&vs[r][cq*4] =
          *(const float4*)(qkv + (size_t)((c*JCH + r)*BATCH + b)*E3 + 2*EMB + h*HD + cq*4);
      }
      __syncthreads();
      #pragma unroll
      for (int sub = 0; sub < JCH/32; ++sub) {
        const int jj = jt + sub*32;
        float p = __expf(ssave[c*4 + sub] - m) * linv;
        pch[irow][jj] = p;
        size_t aw = ((size_t)b*LSEQ + (i0+irow))*LSEQ + (size_t)c*JCH + jj;
        if (h == 0) attnW[aw] = p * (1.f/NH);   // fresh write: replay-safe
        else        attnW[aw] += p * (1.f/NH);  // exclusive to this block/thread
      }
      __syncthreads();
      #pragma unroll 8
      for (int jj0 = 0; jj0 < JCH/2; ++jj0) {
        const int jj = jh*(JCH/2) + jj0;
        float4 vv = *(const float4*)&vs[jj][dq*4];
        float p = pch[ii][jj];
        acc4.x = fmaf(p, vv.x, acc4.x);
        acc4.y = fmaf(p, vv.y, acc4.y);
        acc4.z = fmaf(p, vv.z, acc4.z);
        acc4.w = fmaf(p, vv.w, acc4.w);
      }
    }
    __syncthreads();
    if (jh == 1) *(float4*)&pvred[ii][dq*4] = acc4;
    __syncthreads();
    if (jh == 0) {
      float4 o = *(const float4*)&pvred[ii][dq*4];
      o.x += acc4.x; o.y += acc4.y; o.z += acc4.z; o.w += acc4.w;
      *(float4*)(attnO + ((size_t)(i0+ii)*BATCH + b)*EMB + h*HD + dq*4) = o;
    }
  }
}

// ---------------------------------------------------------------------------
extern "C" void kernel_launch(void* const* d_in, const int* in_sizes, int n_in,
                              void* d_out, int out_size, void* d_ws, size_t ws_size,
                              hipStream_t stream) {
  (void)in_sizes; (void)n_in; (void)out_size; (void)ws_size;
  const float* query     = (const float*)d_in[0];
  // d_in[1]=key, d_in[2]=value: unused by the reference.
  const float* in_proj_w = (const float*)d_in[3];
  const float* in_proj_b = (const float*)d_in[4];
  const float* s1        = (const float*)d_in[5];
  const float* sh1       = (const float*)d_in[6];
  const float* s2        = (const float*)d_in[7];
  const float* sh2       = (const float*)d_in[8];
  const float* out_w     = (const float*)d_in[9];
  const float* out_b     = (const float*)d_in[10];
  const float* l1_dw     = (const float*)d_in[11];
  const float* l1_db     = (const float*)d_in[12];
  const float* l1_uw     = (const float*)d_in[13];
  const float* l1_ub     = (const float*)d_in[14];
  const float* l1_s      = (const float*)d_in[15];
  const float* l2_dw     = (const float*)d_in[16];
  const float* l2_db     = (const float*)d_in[17];
  const float* l2_uw     = (const float*)d_in[18];
  const float* l2_ub     = (const float*)d_in[19];
  const float* l2_s      = (const float*)d_in[20];

  float* out2  = (float*)d_out;                      // (L,B,E)
  float* attnW = out2 + (size_t)LSEQ*BATCH*EMB;      // (B,L,L)

  // Workspace layout (f32): needs 16,252,928 floats = ~62 MB
  float* ws   = (float*)d_ws;
  float* qkv  = ws;                                  // LB*E3  = 9,437,184
  float* t1   = qkv  + (size_t)LB*E3;                // LB*RNK =   262,144
  float* attn = t1   + (size_t)LB*RNK;               // LB*EMB = 3,145,728
  float* out1 = attn + (size_t)LB*EMB;               // LB*EMB = 3,145,728
  float* t2   = out1 + (size_t)LB*EMB;               // LB*RNK =   262,144

  dim3 blk(256);
  // t1 = relu(query @ l1_dw^T + l1_db)
  gemm_fused<32,64,true,false,false,false><<<dim3(LB/32,1),blk,0,stream>>>(
      query, l1_dw, l1_db, nullptr, nullptr, nullptr, nullptr, nullptr, nullptr,
      t1, LB, RNK, EMB);
  // qkv = ((query @ W^T + b)*s1 + sh1) + (t1 @ l1_uw^T + l1_ub)*l1_s ; q *= 0.125
  gemm_fused<128,128,false,true,true,true><<<dim3(LB/128, E3/128),blk,0,stream>>>(
      query, in_proj_w, in_proj_b, s1, sh1, t1, l1_uw, l1_ub, l1_s,
      qkv, LB, E3, EMB);
  // attention: attn (L,B,E) and attnW (B,L,L)
  attn_fused<<<dim3(LSEQ/16, BATCH), dim3(512), 0, stream>>>(qkv, attn, attnW);
  // out1 = attn @ out_w^T + out_b
  gemm_fused<128,128,false,false,false,false><<<dim3(LB/128, EMB/128),blk,0,stream>>>(
      attn, out_w, out_b, nullptr, nullptr, nullptr, nullptr, nullptr, nullptr,
      out1, LB, EMB, EMB);
  // t2 = relu(out1 @ l2_dw^T + l2_db)
  gemm_fused<32,64,true,false,false,false><<<dim3(LB/32,1),blk,0,stream>>>(
      out1, l2_dw, l2_db, nullptr, nullptr, nullptr, nullptr, nullptr, nullptr,
      t2, LB, RNK, EMB);
  // out2 = (out1 @ out_w^T + out_b)*s2 + sh2 + (t2 @ l2_uw^T + l2_ub)*l2_s
  gemm_fused<128,128,false,true,true,false><<<dim3(LB/128, EMB/128),blk,0,stream>>>(
      out1, out_w, out_b, s2, sh2, t2, l2_uw, l2_ub, l2_s,
      out2, LB, EMB, EMB);
}

// Round 2
// 1336.068 us; speedup vs baseline: 1.7452x; 1.7452x over previous
//
#include <hip/hip_runtime.h>

// Problem constants (L,B,E,H,R) = (2048, 2, 768, 12, 64)
#define LSEQ 2048
#define BATCH 2
#define EMB 768
#define NH 12
#define HD 64
#define RNK 64
#define E3 2304            // 3*EMB
#define LB (LSEQ*BATCH)    // 4096 rows, row index r = i*BATCH + b

// ---------------------------------------------------------------------------
// Generic f32 tiled GEMM:  C = epilogue( A(M,K) @ W(N,K)^T )   (unchanged)
// ---------------------------------------------------------------------------
#define GEMM_TILE_LOOP(PTRA, LDA, PTRB, LDB, KLEN, AMUL)                          \
  for (int k0 = 0; k0 < (KLEN); k0 += BK) {                                       \
    for (int idx = (int)threadIdx.x; idx < BM*4; idx += 256) {                    \
      int r = idx >> 2, cq = idx & 3;                                             \
      float4 t4 = *(const float4*)((PTRA) + (size_t)(row0+r)*(LDA) + k0 + cq*4);  \
      As[cq*4+0][r] = t4.x * (AMUL);                                              \
      As[cq*4+1][r] = t4.y * (AMUL);                                              \
      As[cq*4+2][r] = t4.z * (AMUL);                                              \
      As[cq*4+3][r] = t4.w * (AMUL);                                              \
    }                                                                             \
    for (int idx = (int)threadIdx.x; idx < BN*4; idx += 256) {                    \
      int r = idx >> 2, cq = idx & 3;                                             \
      float4 t4 = *(const float4*)((PTRB) + (size_t)(col0+r)*(LDB) + k0 + cq*4);  \
      Bs[cq*4+0][r] = t4.x;                                                       \
      Bs[cq*4+1][r] = t4.y;                                                       \
      Bs[cq*4+2][r] = t4.z;                                                       \
      Bs[cq*4+3][r] = t4.w;                                                       \
    }                                                                             \
    __syncthreads();                                                              \
    _Pragma("unroll")                                                             \
    for (int k = 0; k < BK; ++k) {                                                \
      float a[TM], bb[TN];                                                        \
      _Pragma("unroll")                                                           \
      for (int i = 0; i < TM; ++i) a[i] = As[k][ty*TM+i];                         \
      _Pragma("unroll")                                                           \
      for (int j = 0; j < TN; ++j) bb[j] = Bs[k][tx*TN+j];                        \
      _Pragma("unroll")                                                           \
      for (int i = 0; i < TM; ++i)                                                \
        _Pragma("unroll")                                                         \
        for (int j = 0; j < TN; ++j) acc[i][j] = fmaf(a[i], bb[j], acc[i][j]);    \
    }                                                                             \
    __syncthreads();                                                              \
  }

template<int BM, int BN, bool RELU, bool LORA, bool SSF, bool QSCALE>
__global__ __launch_bounds__(256) void gemm_fused(
    const float* __restrict__ A, const float* __restrict__ W,
    const float* __restrict__ bias,
    const float* __restrict__ scale, const float* __restrict__ shift,
    const float* __restrict__ Tm, const float* __restrict__ U,
    const float* __restrict__ ub, const float* __restrict__ ls,
    float* __restrict__ C, int M, int N, int K)
{
  (void)M;
  constexpr int BK = 16;
  constexpr int TM = BM / 16, TN = BN / 16;
  __shared__ float As[BK][BM+4];
  __shared__ float Bs[BK][BN+4];
  const int tx = (int)threadIdx.x & 15, ty = (int)threadIdx.x >> 4;
  const int row0 = blockIdx.x * BM, col0 = blockIdx.y * BN;

  float acc[TM][TN];
  #pragma unroll
  for (int i = 0; i < TM; ++i)
    #pragma unroll
    for (int j = 0; j < TN; ++j) acc[i][j] = 0.f;

  GEMM_TILE_LOOP(A, K, W, K, K, 1.0f)

  float lsv = 0.f;
  if constexpr (LORA) lsv = ls[0];

  #pragma unroll
  for (int i = 0; i < TM; ++i) {
    #pragma unroll
    for (int j = 0; j < TN; ++j) {
      const int c = col0 + tx*TN + j;
      float v = acc[i][j] + bias[c];
      if constexpr (SSF)  v = v*scale[c] + shift[c];
      if constexpr (LORA) v += ub[c]*lsv;
      acc[i][j] = v;
    }
  }

  if constexpr (LORA) {
    GEMM_TILE_LOOP(Tm, RNK, U, RNK, RNK, lsv)
  }

  #pragma unroll
  for (int i = 0; i < TM; ++i) {
    const int r = row0 + ty*TM + i;
    #pragma unroll
    for (int j = 0; j < TN; ++j) {
      const int c = col0 + tx*TN + j;
      float v = acc[i][j];
      if constexpr (QSCALE) { if (c < EMB) v *= 0.125f; }  // hd^-0.5
      if constexpr (RELU)   v = fmaxf(v, 0.f);
      C[(size_t)r*N + c] = v;
    }
  }
}

// ---------------------------------------------------------------------------
// flash_attn: head-parallel single-pass flash attention (f32).
//  grid (LSEQ/64, B, H), block 256. 64 q-rows per block, j-chunks of 64.
//  Thread tile 4x4 (rows rg+16i, cols jg+16jj -- strided for bank spread).
//  Outputs: attnO (L,B,E) and per-row stats ml[b][h][i] = {m, l}.
//  attn_weights are NOT produced here (see attnw_kernel).
// ---------------------------------------------------------------------------
__global__ __launch_bounds__(256) void flash_attn(
    const float* __restrict__ qkv, float* __restrict__ attnO,
    float* __restrict__ ml)
{
  const int i0 = blockIdx.x * 64;
  const int b  = blockIdx.y;
  const int h  = blockIdx.z;
  const int t  = (int)threadIdx.x;

  __shared__ float qs[64][68];   // stride 68 floats = 272 B = 17*16B (f4-aligned)
  __shared__ float ks[64][68];
  __shared__ float vs[64][68];
  __shared__ float ps[64][68];
  __shared__ float rowm[64], rowl[64], rowa[64];

  // stage Q (rows i0..i0+63, head h); q is pre-scaled by 0.125 in qkv
  for (int idx = t; idx < 64*16; idx += 256) {
    int r = idx >> 4, dq = idx & 15;
    *(float4*)&qs[r][dq*4] =
      *(const float4*)(qkv + (size_t)((i0+r)*BATCH + b)*E3 + h*HD + dq*4);
  }
  if (t < 64) { rowm[t] = -3.0e38f; rowl[t] = 0.f; }

  const int rg = t >> 4;   // rows rg + 16*i
  const int jg = t & 15;   // score cols jg + 16*jj ; PV d = jg*4..jg*4+3
  float acc[4][4];
  #pragma unroll
  for (int i = 0; i < 4; ++i)
    #pragma unroll
    for (int j = 0; j < 4; ++j) acc[i][j] = 0.f;

  for (int c = 0; c < LSEQ/64; ++c) {
    __syncthreads();   // protects ks/vs reuse + first-iter qs/rowm visibility
    for (int idx = t; idx < 64*16; idx += 256) {
      int r = idx >> 4, dq = idx & 15;
      size_t base = (size_t)((c*64+r)*BATCH + b)*E3 + h*HD + dq*4;
      *(float4*)&ks[r][dq*4] = *(const float4*)(qkv + base + EMB);
      *(float4*)&vs[r][dq*4] = *(const float4*)(qkv + base + 2*EMB);
    }
    __syncthreads();

    // ---- scores: sc[i][jj] = q[rg+16i] . k[jg+16jj] ----
    float sc[4][4];
    #pragma unroll
    for (int i = 0; i < 4; ++i)
      #pragma unroll
      for (int j = 0; j < 4; ++j) sc[i][j] = 0.f;
    #pragma unroll
    for (int dq = 0; dq < 16; ++dq) {
      float4 kk[4];
      #pragma unroll
      for (int jj = 0; jj < 4; ++jj) kk[jj] = *(const float4*)&ks[jg+16*jj][dq*4];
      #pragma unroll
      for (int i = 0; i < 4; ++i) {
        float4 qq = *(const float4*)&qs[rg+16*i][dq*4];
        #pragma unroll
        for (int jj = 0; jj < 4; ++jj) {
          sc[i][jj] = fmaf(qq.x, kk[jj].x, sc[i][jj]);
          sc[i][jj] = fmaf(qq.y, kk[jj].y, sc[i][jj]);
          sc[i][jj] = fmaf(qq.z, kk[jj].z, sc[i][jj]);
          sc[i][jj] = fmaf(qq.w, kk[jj].w, sc[i][jj]);
        }
      }
    }
    #pragma unroll
    for (int i = 0; i < 4; ++i)
      #pragma unroll
      for (int jj = 0; jj < 4; ++jj)
        ps[rg+16*i][jg+16*jj] = sc[i][jj];
    __syncthreads();

    // ---- online softmax update: 8 threads per row, 2 passes of 32 rows ----
    #pragma unroll
    for (int pass = 0; pass < 2; ++pass) {
      const int rr = (t >> 3) + 32*pass;
      const int tj = t & 7;
      float e[8];
      float4 a0 = *(const float4*)&ps[rr][tj*8];
      float4 a1 = *(const float4*)&ps[rr][tj*8+4];
      e[0]=a0.x; e[1]=a0.y; e[2]=a0.z; e[3]=a0.w;
      e[4]=a1.x; e[5]=a1.y; e[6]=a1.z; e[7]=a1.w;
      float mx = e[0];
      #pragma unroll
      for (int u = 1; u < 8; ++u) mx = fmaxf(mx, e[u]);
      #pragma unroll
      for (int off = 1; off < 8; off <<= 1) mx = fmaxf(mx, __shfl_xor(mx, off));
      const float mold = rowm[rr];
      const float mnew = fmaxf(mold, mx);
      float sum = 0.f;
      #pragma unroll
      for (int u = 0; u < 8; ++u) { e[u] = __expf(e[u] - mnew); sum += e[u]; }
      #pragma unroll
      for (int off = 1; off < 8; off <<= 1) sum += __shfl_xor(sum, off);
      *(float4*)&ps[rr][tj*8]   = make_float4(e[0],e[1],e[2],e[3]);
      *(float4*)&ps[rr][tj*8+4] = make_float4(e[4],e[5],e[6],e[7]);
      if (tj == 0) {
        float al = __expf(mold - mnew);
        rowa[rr] = al;
        rowl[rr] = rowl[rr]*al + sum;
        rowm[rr] = mnew;
      }
    }
    __syncthreads();

    // ---- rescale + PV: acc[i][d] += sum_j p[rg+16i][j] * v[j][jg*4+d] ----
    #pragma unroll
    for (int i = 0; i < 4; ++i) {
      const float al = rowa[rg+16*i];
      #pragma unroll
      for (int j = 0; j < 4; ++j) acc[i][j] *= al;
    }
    #pragma unroll
    for (int j4 = 0; j4 < 16; ++j4) {
      float4 vv[4];
      #pragma unroll
      for (int u = 0; u < 4; ++u) vv[u] = *(const float4*)&vs[j4*4+u][jg*4];
      #pragma unroll
      for (int i = 0; i < 4; ++i) {
        float4 pp = *(const float4*)&ps[rg+16*i][j4*4];
        acc[i][0] = fmaf(pp.x, vv[0].x, fmaf(pp.y, vv[1].x, fmaf(pp.z, vv[2].x, fmaf(pp.w, vv[3].x, acc[i][0]))));
        acc[i][1] = fmaf(pp.x, vv[0].y, fmaf(pp.y, vv[1].y, fmaf(pp.z, vv[2].y, fmaf(pp.w, vv[3].y, acc[i][1]))));
        acc[i][2] = fmaf(pp.x, vv[0].z, fmaf(pp.y, vv[1].z, fmaf(pp.z, vv[2].z, fmaf(pp.w, vv[3].z, acc[i][2]))));
        acc[i][3] = fmaf(pp.x, vv[0].w, fmaf(pp.y, vv[1].w, fmaf(pp.z, vv[2].w, fmaf(pp.w, vv[3].w, acc[i][3]))));
      }
    }
  }

  // epilogue: normalize + write attn output, dump (m,l) stats
  #pragma unroll
  for (int i = 0; i < 4; ++i) {
    const int r = rg + 16*i;
    const float inv = 1.f / rowl[r];
    float4 o = make_float4(acc[i][0]*inv, acc[i][1]*inv, acc[i][2]*inv, acc[i][3]*inv);
    *(float4*)(attnO + (size_t)((i0+r)*BATCH + b)*EMB + h*HD + jg*4) = o;
  }
  if (t < 64) {
    size_t base = ((size_t)(b*NH + h)*LSEQ + i0 + t)*2;
    ml[base]   = rowm[t];
    ml[base+1] = rowl[t];
  }
}

// ---------------------------------------------------------------------------
// attnw_kernel: attn_weights = mean_h softmax(scores) computed directly as a
// K=768 segmented GEMM over qkv (q pre-scaled): every 64 k's (= one head),
// fold exp(acc - m_h[i]) * (1/(12 l_h[i])) into the output accumulator.
// 128x128 block tile, 8x8 per-thread fragments (2x f4 pairs each axis),
// writes attnW exactly once -- deterministic, no atomics, no RMW.
// ---------------------------------------------------------------------------
__global__ __launch_bounds__(256) void attnw_kernel(
    const float* __restrict__ qkv, const float* __restrict__ ml,
    float* __restrict__ attnW)
{
  const int j0 = blockIdx.x * 128;
  const int i0 = blockIdx.y * 128;
  const int b  = blockIdx.z;
  const int t  = (int)threadIdx.x;
  const int tx = t & 15, ty = t >> 4;

  __shared__ float As[16][132];   // [k][i], 132*4=528 B stride (16B-aligned)
  __shared__ float Bs[16][132];   // [k][j]
  __shared__ float mh[NH][128];
  __shared__ float wh[NH][128];

  for (int idx = t; idx < NH*128; idx += 256) {
    int hh = idx >> 7, r = idx & 127;
    const float* p = ml + ((size_t)(b*NH + hh)*LSEQ + i0 + r)*2;
    mh[hh][r] = p[0];
    wh[hh][r] = (1.0f/NH) / p[1];
  }

  float acc[8][8], fin[8][8];
  #pragma unroll
  for (int i = 0; i < 8; ++i)
    #pragma unroll
    for (int j = 0; j < 8; ++j) { acc[i][j] = 0.f; fin[i][j] = 0.f; }

  for (int k0 = 0; k0 < EMB; k0 += 16) {
    __syncthreads();
    for (int idx = t; idx < 128*4; idx += 256) {
      int r = idx >> 2, cq = idx & 3;
      float4 a4 = *(const float4*)(qkv + (size_t)((i0+r)*BATCH + b)*E3 + k0 + cq*4);
      As[cq*4+0][r] = a4.x; As[cq*4+1][r] = a4.y; As[cq*4+2][r] = a4.z; As[cq*4+3][r] = a4.w;
      float4 b4 = *(const float4*)(qkv + (size_t)((j0+r)*BATCH + b)*E3 + EMB + k0 + cq*4);
      Bs[cq*4+0][r] = b4.x; Bs[cq*4+1][r] = b4.y; Bs[cq*4+2][r] = b4.z; Bs[cq*4+3][r] = b4.w;
    }
    __syncthreads();
    #pragma unroll
    for (int k = 0; k < 16; ++k) {
      float a_[8], b_[8];
      *(float4*)&a_[0] = *(const float4*)&As[k][ty*4];
      *(float4*)&a_[4] = *(const float4*)&As[k][ty*4 + 64];
      *(float4*)&b_[0] = *(const float4*)&Bs[k][tx*4];
      *(float4*)&b_[4] = *(const float4*)&Bs[k][tx*4 + 64];
      #pragma unroll
      for (int i = 0; i < 8; ++i)
        #pragma unroll
        for (int j = 0; j < 8; ++j)
          acc[i][j] = fmaf(a_[i], b_[j], acc[i][j]);
    }
    if (((k0 + 16) & 63) == 0) {           // end of a 64-wide head segment
      const int hh = k0 >> 6;
      #pragma unroll
      for (int i = 0; i < 8; ++i) {
        const int r = ty*4 + (i>>2)*64 + (i&3);
        const float m_ = mh[hh][r], w_ = wh[hh][r];
        #pragma unroll
        for (int j = 0; j < 8; ++j) {
          fin[i][j] = fmaf(__expf(acc[i][j] - m_), w_, fin[i][j]);
          acc[i][j] = 0.f;
        }
      }
    }
  }

  #pragma unroll
  for (int i = 0; i < 8; ++i) {
    const int r = i0 + ty*4 + (i>>2)*64 + (i&3);
    #pragma unroll
    for (int jh = 0; jh < 2; ++jh) {
      float4 o = make_float4(fin[i][jh*4+0], fin[i][jh*4+1], fin[i][jh*4+2], fin[i][jh*4+3]);
      *(float4*)(attnW + ((size_t)b*LSEQ + r)*LSEQ + j0 + tx*4 + jh*64) = o;
    }
  }
}

// ---------------------------------------------------------------------------
extern "C" void kernel_launch(void* const* d_in, const int* in_sizes, int n_in,
                              void* d_out, int out_size, void* d_ws, size_t ws_size,
                              hipStream_t stream) {
  (void)in_sizes; (void)n_in; (void)out_size; (void)ws_size;
  const float* query     = (const float*)d_in[0];
  // d_in[1]=key, d_in[2]=value: unused by the reference.
  const float* in_proj_w = (const float*)d_in[3];
  const float* in_proj_b = (const float*)d_in[4];
  const float* s1        = (const float*)d_in[5];
  const float* sh1       = (const float*)d_in[6];
  const float* s2        = (const float*)d_in[7];
  const float* sh2       = (const float*)d_in[8];
  const float* out_w     = (const float*)d_in[9];
  const float* out_b     = (const float*)d_in[10];
  const float* l1_dw     = (const float*)d_in[11];
  const float* l1_db     = (const float*)d_in[12];
  const float* l1_uw     = (const float*)d_in[13];
  const float* l1_ub     = (const float*)d_in[14];
  const float* l1_s      = (const float*)d_in[15];
  const float* l2_dw     = (const float*)d_in[16];
  const float* l2_db     = (const float*)d_in[17];
  const float* l2_uw     = (const float*)d_in[18];
  const float* l2_ub     = (const float*)d_in[19];
  const float* l2_s      = (const float*)d_in[20];

  float* out2  = (float*)d_out;                      // (L,B,E)
  float* attnW = out2 + (size_t)LSEQ*BATCH*EMB;      // (B,L,L)

  // Workspace layout (f32): 16,252,928 floats ~= 62 MB (unchanged from R1)
  float* ws   = (float*)d_ws;
  float* qkv  = ws;                                  // LB*E3  = 9,437,184
  float* t1   = qkv  + (size_t)LB*E3;                // LB*RNK =   262,144
  float* attn = t1   + (size_t)LB*RNK;               // LB*EMB = 3,145,728
  float* out1 = attn + (size_t)LB*EMB;               // LB*EMB = 3,145,728
  float* t2   = out1 + (size_t)LB*EMB;               // LB*RNK =   262,144
  float* ml   = t1;  // (B,NH,LSEQ,2) = 98,304 floats; t1 is dead after qkv GEMM

  dim3 blk(256);
  // t1 = relu(query @ l1_dw^T + l1_db)
  gemm_fused<32,64,true,false,false,false><<<dim3(LB/32,1),blk,0,stream>>>(
      query, l1_dw, l1_db, nullptr, nullptr, nullptr, nullptr, nullptr, nullptr,
      t1, LB, RNK, EMB);
  // qkv = ((query @ W^T + b)*s1 + sh1) + (t1 @ l1_uw^T + l1_ub)*l1_s ; q *= 0.125
  gemm_fused<128,128,false,true,true,true><<<dim3(LB/128, E3/128),blk,0,stream>>>(
      query, in_proj_w, in_proj_b, s1, sh1, t1, l1_uw, l1_ub, l1_s,
      qkv, LB, E3, EMB);
  // attention output + per-row (m,l) stats   [t1 -> ml alias is safe here]
  flash_attn<<<dim3(LSEQ/64, BATCH, NH), dim3(256), 0, stream>>>(qkv, attn, ml);
  // attn_weights = mean over heads, computed directly (writes once)
  attnw_kernel<<<dim3(LSEQ/128, LSEQ/128, BATCH), dim3(256), 0, stream>>>(qkv, ml, attnW);
  // out1 = attn @ out_w^T + out_b
  gemm_fused<128,128,false,false,false,false><<<dim3(LB/128, EMB/128),blk,0,stream>>>(
      attn, out_w, out_b, nullptr, nullptr, nullptr, nullptr, nullptr, nullptr,
      out1, LB, EMB, EMB);
  // t2 = relu(out1 @ l2_dw^T + l2_db)
  gemm_fused<32,64,true,false,false,false><<<dim3(LB/32,1),blk,0,stream>>>(
      out1, l2_dw, l2_db, nullptr, nullptr, nullptr, nullptr, nullptr, nullptr,
      t2, LB, RNK, EMB);
  // out2 = (out1 @ out_w^T + out_b)*s2 + sh2 + (t2 @ l2_uw^T + l2_ub)*l2_s
  gemm_fused<128,128,false,true,true,false><<<dim3(LB/128, EMB/128),blk,0,stream>>>(
      out1, out_w, out_b, s2, sh2, t2, l2_uw, l2_ub, l2_s,
      out2, LB, EMB, EMB);
}

// Round 3
// 896.536 us; speedup vs baseline: 2.6008x; 1.4903x over previous
//
#include <hip/hip_runtime.h>

// Problem constants (L,B,E,H,R) = (2048, 2, 768, 12, 64)
#define LSEQ 2048
#define BATCH 2
#define EMB 768
#define NH 12
#define HD 64
#define RNK 64
#define E3 2304            // 3*EMB
#define LB (LSEQ*BATCH)    // 4096 rows, row index r = i*BATCH + b

typedef short short8 __attribute__((ext_vector_type(8)));
typedef float f32x16 __attribute__((ext_vector_type(16)));
typedef int   int4v  __attribute__((ext_vector_type(4)));

#define MFMA32(acc, a, b) acc = __builtin_amdgcn_mfma_f32_32x32x16_bf16(a, b, acc, 0, 0, 0)

// split two f32 into packed bf16 hi (truncate) + bf16 lo (truncate of residual).
// pair accuracy: |x - (hi+lo)| <= 2^-16 |x|  (lo absorbs hi's truncation error)
__device__ __forceinline__ void bsplit2(float x0, float x1, unsigned& hp, unsigned& lp) {
  unsigned u0 = __float_as_uint(x0), u1 = __float_as_uint(x1);
  hp = (u0 >> 16) | (u1 & 0xffff0000u);
  float l0 = x0 - __uint_as_float(u0 & 0xffff0000u);
  float l1 = x1 - __uint_as_float(u1 & 0xffff0000u);
  lp = (__float_as_uint(l0) >> 16) | (__float_as_uint(l1) & 0xffff0000u);
}

// split 8 f32 -> short8 hi-plane + short8 lo-plane, store to LDS (16B aligned)
__device__ __forceinline__ void split_store(float4 f0, float4 f1,
                                            short* __restrict__ ph,
                                            short* __restrict__ pl) {
  unsigned h0,h1,h2,h3, l0,l1,l2,l3;
  bsplit2(f0.x, f0.y, h0, l0);
  bsplit2(f0.z, f0.w, h1, l1);
  bsplit2(f1.x, f1.y, h2, l2);
  bsplit2(f1.z, f1.w, h3, l3);
  *(int4v*)ph = (int4v){(int)h0,(int)h1,(int)h2,(int)h3};
  *(int4v*)pl = (int4v){(int)l0,(int)l1,(int)l2,(int)l3};
}

// ---------------------------------------------------------------------------
// gemm_mfma: C = A(M x K) @ Weff(N x K)^T + cc[c], split-bf16 3-pass MFMA.
//   Weff[n][k] = W[n][k] * (wrs?wrs[n]:1) * (wqsc && n<EMB ? 0.125 : 1)
//   LORA: extra K=64 segment A2(M x 64) @ (W2[n][k]*ls*(wqsc&&n<EMB?0.125:1))^T
//   cc[c] = (bias[c]*scale[c]+shift[c] + ub[c]*ls) * (cqsc&&c<EMB ? 0.125 : 1)
// 128x128 tile, BK=32, 4 waves of 64x64, 32x32x16 bf16 MFMA (12 per k-sub).
// LDS planes padded: quad stride 1056 shorts (2112B) -> 2-way (free) banks.
// ---------------------------------------------------------------------------
template<bool LORA>
__global__ __launch_bounds__(256, 1) void gemm_mfma(
    const float* __restrict__ A, const float* __restrict__ W,
    const float* __restrict__ wrs, int wqsc,
    const float* __restrict__ A2, const float* __restrict__ W2,
    const float* __restrict__ bias, const float* __restrict__ scale,
    const float* __restrict__ shift, const float* __restrict__ ub,
    const float* __restrict__ lsp, int cqsc,
    float* __restrict__ C, int N, int K)
{
  __shared__ __align__(16) short sAh[4224], sAl[4224], sBh[4224], sBl[4224];
  const int t = (int)threadIdx.x;
  const int row0 = blockIdx.x * 128, col0 = blockIdx.y * 128;
  const float lsv = LORA ? lsp[0] : 0.f;
  const int mainSteps = K >> 5;
  const int totSteps = mainSteps + (LORA ? 2 : 0);

  f32x16 acc[2][2];
  #pragma unroll
  for (int i = 0; i < 2; ++i)
    #pragma unroll
    for (int j = 0; j < 2; ++j)
      #pragma unroll
      for (int r = 0; r < 16; ++r) acc[i][j][r] = 0.f;

  const int lane = t & 63, wv = t >> 6, wm = wv >> 1, wn = wv & 1;
  const int rl = lane & 31, kq = lane >> 5;

  for (int kt = 0; kt < totSteps; ++kt) {
    const bool mn = (kt < mainSteps);
    const int kk = mn ? kt*32 : (kt - mainSteps)*32;
    __syncthreads();
    // ---- stage A: 128x32 f32 -> hi/lo bf16 planes ----
    #pragma unroll
    for (int c = 0; c < 2; ++c) {
      const int id = c*256 + t, row = id >> 2, kO = id & 3;
      const float* src = mn ? (A  + (size_t)(row0+row)*K   + kk + kO*8)
                            : (A2 + (size_t)(row0+row)*RNK + kk + kO*8);
      float4 f0 = *(const float4*)src, f1 = *(const float4*)(src+4);
      split_store(f0, f1, &sAh[kO*1056 + row*8], &sAl[kO*1056 + row*8]);
    }
    // ---- stage B (weights, row-scaled) ----
    #pragma unroll
    for (int c = 0; c < 2; ++c) {
      const int id = c*256 + t, row = id >> 2, kO = id & 3;
      const int n = col0 + row;
      float sc; const float* src;
      if (mn) {
        sc = wrs ? wrs[n] : 1.f;
        if (wqsc && n < EMB) sc *= 0.125f;
        src = W + (size_t)n*K + kk + kO*8;
      } else {
        sc = lsv;
        if (wqsc && n < EMB) sc *= 0.125f;
        src = W2 + (size_t)n*RNK + kk + kO*8;
      }
      float4 f0 = *(const float4*)src, f1 = *(const float4*)(src+4);
      f0.x*=sc; f0.y*=sc; f0.z*=sc; f0.w*=sc;
      f1.x*=sc; f1.y*=sc; f1.z*=sc; f1.w*=sc;
      split_store(f0, f1, &sBh[kO*1056 + row*8], &sBl[kO*1056 + row*8]);
    }
    __syncthreads();
    // ---- 2 k-subs x 12 MFMAs (hh + hl + lh passes) ----
    #pragma unroll
    for (int s = 0; s < 2; ++s) {
      const int kO = s*2 + kq;
      const int ao = kO*1056 + (wm*64 + rl)*8;
      const int bo = kO*1056 + (wn*64 + rl)*8;
      short8 ah0 = *(const short8*)&sAh[ao];
      short8 ah1 = *(const short8*)&sAh[ao + 256];
      short8 al0 = *(const short8*)&sAl[ao];
      short8 al1 = *(const short8*)&sAl[ao + 256];
      short8 bh0 = *(const short8*)&sBh[bo];
      short8 bh1 = *(const short8*)&sBh[bo + 256];
      short8 bl0 = *(const short8*)&sBl[bo];
      short8 bl1 = *(const short8*)&sBl[bo + 256];
      MFMA32(acc[0][0], ah0, bh0); MFMA32(acc[0][1], ah0, bh1);
      MFMA32(acc[1][0], ah1, bh0); MFMA32(acc[1][1], ah1, bh1);
      MFMA32(acc[0][0], ah0, bl0); MFMA32(acc[0][1], ah0, bl1);
      MFMA32(acc[1][0], ah1, bl0); MFMA32(acc[1][1], ah1, bl1);
      MFMA32(acc[0][0], al0, bh0); MFMA32(acc[0][1], al0, bh1);
      MFMA32(acc[1][0], al1, bh0); MFMA32(acc[1][1], al1, bh1);
    }
  }

  // ---- epilogue: C[m][n] = acc + cc[n]  (C/D map: col=lane&31, row=(reg&3)+8*(reg>>2)+4*(lane>>5)) ----
  #pragma unroll
  for (int fj = 0; fj < 2; ++fj) {
    const int c = col0 + wn*64 + fj*32 + rl;
    float ccv = bias ? bias[c] : 0.f;
    if (scale) ccv = ccv*scale[c] + shift[c];
    if (ub)    ccv += ub[c]*lsv;
    if (cqsc && c < EMB) ccv *= 0.125f;
    #pragma unroll
    for (int fi = 0; fi < 2; ++fi) {
      #pragma unroll
      for (int reg = 0; reg < 16; ++reg) {
        const int rr = (reg & 3) + 8*(reg >> 2) + 4*(lane >> 5);
        const int m = row0 + wm*64 + fi*32 + rr;
        C[(size_t)m*N + c] = acc[fi][fj][reg] + ccv;
      }
    }
  }
}

// ---------------------------------------------------------------------------
// attnw_mfma: attn_weights[b][i][j] = sum_h exp(S_h[i][j]-m_h[i]) / (12 l_h[i])
// as a segmented K=768 split-bf16 MFMA GEMM over qkv (q pre-scaled by 0.125);
// fold after every 64-wide head segment using flash_attn's (m,l). Write-once.
// ---------------------------------------------------------------------------
__global__ __launch_bounds__(256, 1) void attnw_mfma(
    const float* __restrict__ qkv, const float* __restrict__ ml,
    float* __restrict__ attnW)
{
  __shared__ __align__(16) short sAh[4224], sAl[4224], sBh[4224], sBl[4224];
  __shared__ float mh[NH][128], wh[NH][128];
  const int t = (int)threadIdx.x;
  const int j0 = blockIdx.x * 128, i0 = blockIdx.y * 128, b = blockIdx.z;

  for (int idx = t; idx < NH*128; idx += 256) {
    const int hh = idx >> 7, r = idx & 127;
    const float* p = ml + ((size_t)(b*NH + hh)*LSEQ + i0 + r)*2;
    mh[hh][r] = p[0];
    wh[hh][r] = (1.0f/NH) / p[1];
  }

  f32x16 acc[2][2], fin[2][2];
  #pragma unroll
  for (int i = 0; i < 2; ++i)
    #pragma unroll
    for (int j = 0; j < 2; ++j)
      #pragma unroll
      for (int r = 0; r < 16; ++r) { acc[i][j][r] = 0.f; fin[i][j][r] = 0.f; }

  const int lane = t & 63, wv = t >> 6, wm = wv >> 1, wn = wv & 1;
  const int rl = lane & 31, kq = lane >> 5;

  for (int kt = 0; kt < EMB/32; ++kt) {
    __syncthreads();   // also covers the mh/wh staging on kt==0
    #pragma unroll
    for (int c = 0; c < 2; ++c) {
      const int id = c*256 + t, row = id >> 2, kO = id & 3;
      const float* sa = qkv + (size_t)((i0+row)*BATCH + b)*E3 + kt*32 + kO*8;
      float4 a0 = *(const float4*)sa, a1 = *(const float4*)(sa+4);
      split_store(a0, a1, &sAh[kO*1056 + row*8], &sAl[kO*1056 + row*8]);
      const float* sb = qkv + (size_t)((j0+row)*BATCH + b)*E3 + EMB + kt*32 + kO*8;
      float4 b0 = *(const float4*)sb, b1 = *(const float4*)(sb+4);
      split_store(b0, b1, &sBh[kO*1056 + row*8], &sBl[kO*1056 + row*8]);
    }
    __syncthreads();
    #pragma unroll
    for (int s = 0; s < 2; ++s) {
      const int kO = s*2 + kq;
      const int ao = kO*1056 + (wm*64 + rl)*8;
      const int bo = kO*1056 + (wn*64 + rl)*8;
      short8 ah0 = *(const short8*)&sAh[ao];
      short8 ah1 = *(const short8*)&sAh[ao + 256];
      short8 al0 = *(const short8*)&sAl[ao];
      short8 al1 = *(const short8*)&sAl[ao + 256];
      short8 bh0 = *(const short8*)&sBh[bo];
      short8 bh1 = *(const short8*)&sBh[bo + 256];
      short8 bl0 = *(const short8*)&sBl[bo];
      short8 bl1 = *(const short8*)&sBl[bo + 256];
      MFMA32(acc[0][0], ah0, bh0); MFMA32(acc[0][1], ah0, bh1);
      MFMA32(acc[1][0], ah1, bh0); MFMA32(acc[1][1], ah1, bh1);
      MFMA32(acc[0][0], ah0, bl0); MFMA32(acc[0][1], ah0, bl1);
      MFMA32(acc[1][0], ah1, bl0); MFMA32(acc[1][1], ah1, bl1);
      MFMA32(acc[0][0], al0, bh0); MFMA32(acc[0][1], al0, bh1);
      MFMA32(acc[1][0], al1, bh0); MFMA32(acc[1][1], al1, bh1);
    }
    if (kt & 1) {                      // completed head segment [kt-1, kt]
      const int hh = kt >> 1;
      #pragma unroll
      for (int fi = 0; fi < 2; ++fi)
        #pragma unroll
        for (int fj = 0; fj < 2; ++fj)
          #pragma unroll
          for (int reg = 0; reg < 16; ++reg) {
            const int rr = (reg & 3) + 8*(reg >> 2) + 4*(lane >> 5);
            const int row = wm*64 + fi*32 + rr;
            fin[fi][fj][reg] += __expf(acc[fi][fj][reg] - mh[hh][row]) * wh[hh][row];
            acc[fi][fj][reg] = 0.f;
          }
    }
  }

  #pragma unroll
  for (int fj = 0; fj < 2; ++fj) {
    const int j = j0 + wn*64 + fj*32 + rl;
    #pragma unroll
    for (int fi = 0; fi < 2; ++fi) {
      #pragma unroll
      for (int reg = 0; reg < 16; ++reg) {
        const int rr = (reg & 3) + 8*(reg >> 2) + 4*(lane >> 5);
        const int i = i0 + wm*64 + fi*32 + rr;
        attnW[((size_t)b*LSEQ + i)*LSEQ + j] = fin[fi][fj][reg];
      }
    }
  }
}

// ---------------------------------------------------------------------------
// gemm_lora: T = relu(A(M x 768) @ Wd(64 x 768)^T + db)   (f32 vector, small)
// ---------------------------------------------------------------------------
__global__ __launch_bounds__(256) void gemm_lora(
    const float* __restrict__ A, const float* __restrict__ Wd,
    const float* __restrict__ db, float* __restrict__ T)
{
  __shared__ float As[16][36];
  __shared__ float Bs[16][68];
  const int tx = (int)threadIdx.x & 15, ty = (int)threadIdx.x >> 4;
  const int row0 = blockIdx.x * 32;
  float acc[2][4];
  #pragma unroll
  for (int i = 0; i < 2; ++i)
    #pragma unroll
    for (int j = 0; j < 4; ++j) acc[i][j] = 0.f;

  for (int k0 = 0; k0 < EMB; k0 += 16) {
    for (int idx = (int)threadIdx.x; idx < 32*4; idx += 256) {
      int r = idx >> 2, cq = idx & 3;
      float4 t4 = *(const float4*)(A + (size_t)(row0+r)*EMB + k0 + cq*4);
      As[cq*4+0][r]=t4.x; As[cq*4+1][r]=t4.y; As[cq*4+2][r]=t4.z; As[cq*4+3][r]=t4.w;
    }
    for (int idx = (int)threadIdx.x; idx < 64*4; idx += 256) {
      int r = idx >> 2, cq = idx & 3;
      float4 t4 = *(const float4*)(Wd + (size_t)r*EMB + k0 + cq*4);
      Bs[cq*4+0][r]=t4.x; Bs[cq*4+1][r]=t4.y; Bs[cq*4+2][r]=t4.z; Bs[cq*4+3][r]=t4.w;
    }
    __syncthreads();
    #pragma unroll
    for (int k = 0; k < 16; ++k) {
      float a0 = As[k][ty*2], a1 = As[k][ty*2+1];
      #pragma unroll
      for (int j = 0; j < 4; ++j) {
        float bb = Bs[k][tx*4+j];
        acc[0][j] = fmaf(a0, bb, acc[0][j]);
        acc[1][j] = fmaf(a1, bb, acc[1][j]);
      }
    }
    __syncthreads();
  }
  #pragma unroll
  for (int i = 0; i < 2; ++i) {
    const int r = row0 + ty*2 + i;
    #pragma unroll
    for (int j = 0; j < 4; ++j) {
      const int c = tx*4 + j;
      T[(size_t)r*RNK + c] = fmaxf(acc[i][j] + db[c], 0.f);
    }
  }
}

// ---------------------------------------------------------------------------
// flash_attn: unchanged from round 2 (f32 vector; MFMA conversion next round)
// ---------------------------------------------------------------------------
__global__ __launch_bounds__(256) void flash_attn(
    const float* __restrict__ qkv, float* __restrict__ attnO,
    float* __restrict__ ml)
{
  const int i0 = blockIdx.x * 64;
  const int b  = blockIdx.y;
  const int h  = blockIdx.z;
  const int t  = (int)threadIdx.x;

  __shared__ float qs[64][68];
  __shared__ float ks[64][68];
  __shared__ float vs[64][68];
  __shared__ float ps[64][68];
  __shared__ float rowm[64], rowl[64], rowa[64];

  for (int idx = t; idx < 64*16; idx += 256) {
    int r = idx >> 4, dq = idx & 15;
    *(float4*)&qs[r][dq*4] =
      *(const float4*)(qkv + (size_t)((i0+r)*BATCH + b)*E3 + h*HD + dq*4);
  }
  if (t < 64) { rowm[t] = -3.0e38f; rowl[t] = 0.f; }

  const int rg = t >> 4;
  const int jg = t & 15;
  float acc[4][4];
  #pragma unroll
  for (int i = 0; i < 4; ++i)
    #pragma unroll
    for (int j = 0; j < 4; ++j) acc[i][j] = 0.f;

  for (int c = 0; c < LSEQ/64; ++c) {
    __syncthreads();
    for (int idx = t; idx < 64*16; idx += 256) {
      int r = idx >> 4, dq = idx & 15;
      size_t base = (size_t)((c*64+r)*BATCH + b)*E3 + h*HD + dq*4;
      *(float4*)&ks[r][dq*4] = *(const float4*)(qkv + base + EMB);
      *(float4*)&vs[r][dq*4] = *(const float4*)(qkv + base + 2*EMB);
    }
    __syncthreads();

    float sc[4][4];
    #pragma unroll
    for (int i = 0; i < 4; ++i)
      #pragma unroll
      for (int j = 0; j < 4; ++j) sc[i][j] = 0.f;
    #pragma unroll
    for (int dq = 0; dq < 16; ++dq) {
      float4 kk[4];
      #pragma unroll
      for (int jj = 0; jj < 4; ++jj) kk[jj] = *(const float4*)&ks[jg+16*jj][dq*4];
      #pragma unroll
      for (int i = 0; i < 4; ++i) {
        float4 qq = *(const float4*)&qs[rg+16*i][dq*4];
        #pragma unroll
        for (int jj = 0; jj < 4; ++jj) {
          sc[i][jj] = fmaf(qq.x, kk[jj].x, sc[i][jj]);
          sc[i][jj] = fmaf(qq.y, kk[jj].y, sc[i][jj]);
          sc[i][jj] = fmaf(qq.z, kk[jj].z, sc[i][jj]);
          sc[i][jj] = fmaf(qq.w, kk[jj].w, sc[i][jj]);
        }
      }
    }
    #pragma unroll
    for (int i = 0; i < 4; ++i)
      #pragma unroll
      for (int jj = 0; jj < 4; ++jj)
        ps[rg+16*i][jg+16*jj] = sc[i][jj];
    __syncthreads();

    #pragma unroll
    for (int pass = 0; pass < 2; ++pass) {
      const int rr = (t >> 3) + 32*pass;
      const int tj = t & 7;
      float e[8];
      float4 a0 = *(const float4*)&ps[rr][tj*8];
      float4 a1 = *(const float4*)&ps[rr][tj*8+4];
      e[0]=a0.x; e[1]=a0.y; e[2]=a0.z; e[3]=a0.w;
      e[4]=a1.x; e[5]=a1.y; e[6]=a1.z; e[7]=a1.w;
      float mx = e[0];
      #pragma unroll
      for (int u = 1; u < 8; ++u) mx = fmaxf(mx, e[u]);
      #pragma unroll
      for (int off = 1; off < 8; off <<= 1) mx = fmaxf(mx, __shfl_xor(mx, off));
      const float mold = rowm[rr];
      const float mnew = fmaxf(mold, mx);
      float sum = 0.f;
      #pragma unroll
      for (int u = 0; u < 8; ++u) { e[u] = __expf(e[u] - mnew); sum += e[u]; }
      #pragma unroll
      for (int off = 1; off < 8; off <<= 1) sum += __shfl_xor(sum, off);
      *(float4*)&ps[rr][tj*8]   = make_float4(e[0],e[1],e[2],e[3]);
      *(float4*)&ps[rr][tj*8+4] = make_float4(e[4],e[5],e[6],e[7]);
      if (tj == 0) {
        float al = __expf(mold - mnew);
        rowa[rr] = al;
        rowl[rr] = rowl[rr]*al + sum;
        rowm[rr] = mnew;
      }
    }
    __syncthreads();

    #pragma unroll
    for (int i = 0; i < 4; ++i) {
      const float al = rowa[rg+16*i];
      #pragma unroll
      for (int j = 0; j < 4; ++j) acc[i][j] *= al;
    }
    #pragma unroll
    for (int j4 = 0; j4 < 16; ++j4) {
      float4 vv[4];
      #pragma unroll
      for (int u = 0; u < 4; ++u) vv[u] = *(const float4*)&vs[j4*4+u][jg*4];
      #pragma unroll
      for (int i = 0; i < 4; ++i) {
        float4 pp = *(const float4*)&ps[rg+16*i][j4*4];
        acc[i][0] = fmaf(pp.x, vv[0].x, fmaf(pp.y, vv[1].x, fmaf(pp.z, vv[2].x, fmaf(pp.w, vv[3].x, acc[i][0]))));
        acc[i][1] = fmaf(pp.x, vv[0].y, fmaf(pp.y, vv[1].y, fmaf(pp.z, vv[2].y, fmaf(pp.w, vv[3].y, acc[i][1]))));
        acc[i][2] = fmaf(pp.x, vv[0].z, fmaf(pp.y, vv[1].z, fmaf(pp.z, vv[2].z, fmaf(pp.w, vv[3].z, acc[i][2]))));
        acc[i][3] = fmaf(pp.x, vv[0].w, fmaf(pp.y, vv[1].w, fmaf(pp.z, vv[2].w, fmaf(pp.w, vv[3].w, acc[i][3]))));
      }
    }
  }

  #pragma unroll
  for (int i = 0; i < 4; ++i) {
    const int r = rg + 16*i;
    const float inv = 1.f / rowl[r];
    float4 o = make_float4(acc[i][0]*inv, acc[i][1]*inv, acc[i][2]*inv, acc[i][3]*inv);
    *(float4*)(attnO + (size_t)((i0+r)*BATCH + b)*EMB + h*HD + jg*4) = o;
  }
  if (t < 64) {
    size_t base = ((size_t)(b*NH + h)*LSEQ + i0 + t)*2;
    ml[base]   = rowm[t];
    ml[base+1] = rowl[t];
  }
}

// ---------------------------------------------------------------------------
extern "C" void kernel_launch(void* const* d_in, const int* in_sizes, int n_in,
                              void* d_out, int out_size, void* d_ws, size_t ws_size,
                              hipStream_t stream) {
  (void)in_sizes; (void)n_in; (void)out_size; (void)ws_size;
  const float* query     = (const float*)d_in[0];
  const float* in_proj_w = (const float*)d_in[3];
  const float* in_proj_b = (const float*)d_in[4];
  const float* s1        = (const float*)d_in[5];
  const float* sh1       = (const float*)d_in[6];
  const float* s2        = (const float*)d_in[7];
  const float* sh2       = (const float*)d_in[8];
  const float* out_w     = (const float*)d_in[9];
  const float* out_b     = (const float*)d_in[10];
  const float* l1_dw     = (const float*)d_in[11];
  const float* l1_db     = (const float*)d_in[12];
  const float* l1_uw     = (const float*)d_in[13];
  const float* l1_ub     = (const float*)d_in[14];
  const float* l1_s      = (const float*)d_in[15];
  const float* l2_dw     = (const float*)d_in[16];
  const float* l2_db     = (const float*)d_in[17];
  const float* l2_uw     = (const float*)d_in[18];
  const float* l2_ub     = (const float*)d_in[19];
  const float* l2_s      = (const float*)d_in[20];

  float* out2  = (float*)d_out;                      // (L,B,E)
  float* attnW = out2 + (size_t)LSEQ*BATCH*EMB;      // (B,L,L)

  // Workspace (f32, ~65MB -- identical budget to round 1/2, known safe)
  float* ws   = (float*)d_ws;
  float* qkv  = ws;                                  // LB*E3  = 9,437,184
  float* t1   = qkv  + (size_t)LB*E3;                // LB*RNK =   262,144
  float* attn = t1   + (size_t)LB*RNK;               // LB*EMB = 3,145,728
  float* out1 = attn + (size_t)LB*EMB;               // LB*EMB = 3,145,728
  float* t2   = out1 + (size_t)LB*EMB;               // LB*RNK =   262,144
  float* ml   = t1;  // (B,NH,LSEQ,2); t1 dead after qkv GEMM, before flash

  // t1 = relu(query @ l1_dw^T + l1_db)
  gemm_lora<<<dim3(LB/32), dim3(256), 0, stream>>>(query, l1_dw, l1_db, t1);

  // qkv = ssf1(query@W^T + b) + (t1@l1_uw^T + l1_ub)*l1_s ; cols<768 scaled 0.125
  gemm_mfma<true><<<dim3(LB/128, E3/128), dim3(256), 0, stream>>>(
      query, in_proj_w, s1, 1, t1, l1_uw,
      in_proj_b, s1, sh1, l1_ub, l1_s, 1, qkv, E3, EMB);

  // attention output + per-row (m,l) stats  [ml aliases t1: t1 consumed above]
  flash_attn<<<dim3(LSEQ/64, BATCH, NH), dim3(256), 0, stream>>>(qkv, attn, ml);

  // attn_weights = mean over heads (segmented MFMA GEMM, write-once)
  attnw_mfma<<<dim3(LSEQ/128, LSEQ/128, BATCH), dim3(256), 0, stream>>>(qkv, ml, attnW);

  // out1 = attn @ out_w^T + out_b
  gemm_mfma<false><<<dim3(LB/128, EMB/128), dim3(256), 0, stream>>>(
      attn, out_w, nullptr, 0, nullptr, nullptr,
      out_b, nullptr, nullptr, nullptr, nullptr, 0, out1, EMB, EMB);

  // t2 = relu(out1 @ l2_dw^T + l2_db)
  gemm_lora<<<dim3(LB/32), dim3(256), 0, stream>>>(out1, l2_dw, l2_db, t2);

  // out2 = ssf2(out1@out_w^T + out_b) + (t2@l2_uw^T + l2_ub)*l2_s
  gemm_mfma<true><<<dim3(LB/128, EMB/128), dim3(256), 0, stream>>>(
      out1, out_w, s2, 0, t2, l2_uw,
      out_b, s2, sh2, l2_ub, l2_s, 0, out2, EMB, EMB);
}

// Round 4
// 559.972 us; speedup vs baseline: 4.1640x; 1.6010x over previous
//
#include <hip/hip_runtime.h>

// Problem constants (L,B,E,H,R) = (2048, 2, 768, 12, 64)
#define LSEQ 2048
#define BATCH 2
#define EMB 768
#define NH 12
#define HD 64
#define RNK 64
#define E3 2304            // 3*EMB
#define LB (LSEQ*BATCH)    // 4096 rows, row index r = i*BATCH + b

typedef short short8 __attribute__((ext_vector_type(8)));
typedef float f32x16 __attribute__((ext_vector_type(16)));
typedef int   int4v  __attribute__((ext_vector_type(4)));
typedef int   int2v  __attribute__((ext_vector_type(2)));

#define MFMA32(acc, a, b) acc = __builtin_amdgcn_mfma_f32_32x32x16_bf16(a, b, acc, 0, 0, 0)

// split two f32 into packed bf16 hi (truncate) + bf16 lo (truncate of residual).
__device__ __forceinline__ void bsplit2(float x0, float x1, unsigned& hp, unsigned& lp) {
  unsigned u0 = __float_as_uint(x0), u1 = __float_as_uint(x1);
  hp = (u0 >> 16) | (u1 & 0xffff0000u);
  float l0 = x0 - __uint_as_float(u0 & 0xffff0000u);
  float l1 = x1 - __uint_as_float(u1 & 0xffff0000u);
  lp = (__float_as_uint(l0) >> 16) | (__float_as_uint(l1) & 0xffff0000u);
}

__device__ __forceinline__ unsigned pkhi(float a, float b) {
  return (__float_as_uint(a) >> 16) | (__float_as_uint(b) & 0xffff0000u);
}
__device__ __forceinline__ float hif(float a) {
  return __uint_as_float(__float_as_uint(a) & 0xffff0000u);
}
__device__ __forceinline__ short8 pack4(unsigned a, unsigned b, unsigned c, unsigned d) {
  int4v v = {(int)a, (int)b, (int)c, (int)d};
  return __builtin_bit_cast(short8, v);
}

// split 8 f32 -> short8 hi-plane + short8 lo-plane, store to LDS (16B aligned)
__device__ __forceinline__ void split_store(float4 f0, float4 f1,
                                            short* __restrict__ ph,
                                            short* __restrict__ pl) {
  unsigned h0,h1,h2,h3, l0,l1,l2,l3;
  bsplit2(f0.x, f0.y, h0, l0);
  bsplit2(f0.z, f0.w, h1, l1);
  bsplit2(f1.x, f1.y, h2, l2);
  bsplit2(f1.z, f1.w, h3, l3);
  *(int4v*)ph = (int4v){(int)h0,(int)h1,(int)h2,(int)h3};
  *(int4v*)pl = (int4v){(int)l0,(int)l1,(int)l2,(int)l3};
}

// ---------------------------------------------------------------------------
// gemm_mfma: C = A(M x K) @ Weff(N x K)^T + cc[c], split-bf16 3-pass MFMA.
// (unchanged from round 3)
// ---------------------------------------------------------------------------
template<bool LORA>
__global__ __launch_bounds__(256, 1) void gemm_mfma(
    const float* __restrict__ A, const float* __restrict__ W,
    const float* __restrict__ wrs, int wqsc,
    const float* __restrict__ A2, const float* __restrict__ W2,
    const float* __restrict__ bias, const float* __restrict__ scale,
    const float* __restrict__ shift, const float* __restrict__ ub,
    const float* __restrict__ lsp, int cqsc,
    float* __restrict__ C, int N, int K)
{
  __shared__ __align__(16) short sAh[4224], sAl[4224], sBh[4224], sBl[4224];
  const int t = (int)threadIdx.x;
  const int row0 = blockIdx.x * 128, col0 = blockIdx.y * 128;
  const float lsv = LORA ? lsp[0] : 0.f;
  const int mainSteps = K >> 5;
  const int totSteps = mainSteps + (LORA ? 2 : 0);

  f32x16 acc[2][2];
  #pragma unroll
  for (int i = 0; i < 2; ++i)
    #pragma unroll
    for (int j = 0; j < 2; ++j)
      #pragma unroll
      for (int r = 0; r < 16; ++r) acc[i][j][r] = 0.f;

  const int lane = t & 63, wv = t >> 6, wm = wv >> 1, wn = wv & 1;
  const int rl = lane & 31, kq = lane >> 5;

  for (int kt = 0; kt < totSteps; ++kt) {
    const bool mn = (kt < mainSteps);
    const int kk = mn ? kt*32 : (kt - mainSteps)*32;
    __syncthreads();
    #pragma unroll
    for (int c = 0; c < 2; ++c) {
      const int id = c*256 + t, row = id >> 2, kO = id & 3;
      const float* src = mn ? (A  + (size_t)(row0+row)*K   + kk + kO*8)
                            : (A2 + (size_t)(row0+row)*RNK + kk + kO*8);
      float4 f0 = *(const float4*)src, f1 = *(const float4*)(src+4);
      split_store(f0, f1, &sAh[kO*1056 + row*8], &sAl[kO*1056 + row*8]);
    }
    #pragma unroll
    for (int c = 0; c < 2; ++c) {
      const int id = c*256 + t, row = id >> 2, kO = id & 3;
      const int n = col0 + row;
      float sc; const float* src;
      if (mn) {
        sc = wrs ? wrs[n] : 1.f;
        if (wqsc && n < EMB) sc *= 0.125f;
        src = W + (size_t)n*K + kk + kO*8;
      } else {
        sc = lsv;
        if (wqsc && n < EMB) sc *= 0.125f;
        src = W2 + (size_t)n*RNK + kk + kO*8;
      }
      float4 f0 = *(const float4*)src, f1 = *(const float4*)(src+4);
      f0.x*=sc; f0.y*=sc; f0.z*=sc; f0.w*=sc;
      f1.x*=sc; f1.y*=sc; f1.z*=sc; f1.w*=sc;
      split_store(f0, f1, &sBh[kO*1056 + row*8], &sBl[kO*1056 + row*8]);
    }
    __syncthreads();
    #pragma unroll
    for (int s = 0; s < 2; ++s) {
      const int kO = s*2 + kq;
      const int ao = kO*1056 + (wm*64 + rl)*8;
      const int bo = kO*1056 + (wn*64 + rl)*8;
      short8 ah0 = *(const short8*)&sAh[ao];
      short8 ah1 = *(const short8*)&sAh[ao + 256];
      short8 al0 = *(const short8*)&sAl[ao];
      short8 al1 = *(const short8*)&sAl[ao + 256];
      short8 bh0 = *(const short8*)&sBh[bo];
      short8 bh1 = *(const short8*)&sBh[bo + 256];
      short8 bl0 = *(const short8*)&sBl[bo];
      short8 bl1 = *(const short8*)&sBl[bo + 256];
      MFMA32(acc[0][0], ah0, bh0); MFMA32(acc[0][1], ah0, bh1);
      MFMA32(acc[1][0], ah1, bh0); MFMA32(acc[1][1], ah1, bh1);
      MFMA32(acc[0][0], ah0, bl0); MFMA32(acc[0][1], ah0, bl1);
      MFMA32(acc[1][0], ah1, bl0); MFMA32(acc[1][1], ah1, bl1);
      MFMA32(acc[0][0], al0, bh0); MFMA32(acc[0][1], al0, bh1);
      MFMA32(acc[1][0], al1, bh0); MFMA32(acc[1][1], al1, bh1);
    }
  }

  #pragma unroll
  for (int fj = 0; fj < 2; ++fj) {
    const int c = col0 + wn*64 + fj*32 + rl;
    float ccv = bias ? bias[c] : 0.f;
    if (scale) ccv = ccv*scale[c] + shift[c];
    if (ub)    ccv += ub[c]*lsv;
    if (cqsc && c < EMB) ccv *= 0.125f;
    #pragma unroll
    for (int fi = 0; fi < 2; ++fi) {
      #pragma unroll
      for (int reg = 0; reg < 16; ++reg) {
        const int rr = (reg & 3) + 8*(reg >> 2) + 4*(lane >> 5);
        const int m = row0 + wm*64 + fi*32 + rr;
        C[(size_t)m*N + c] = acc[fi][fj][reg] + ccv;
      }
    }
  }
}

// ---------------------------------------------------------------------------
// attnw_mfma: attn_weights via segmented K=768 split-bf16 MFMA GEMM.
// (unchanged from round 3)
// ---------------------------------------------------------------------------
__global__ __launch_bounds__(256, 1) void attnw_mfma(
    const float* __restrict__ qkv, const float* __restrict__ ml,
    float* __restrict__ attnW)
{
  __shared__ __align__(16) short sAh[4224], sAl[4224], sBh[4224], sBl[4224];
  __shared__ float mh[NH][128], wh[NH][128];
  const int t = (int)threadIdx.x;
  const int j0 = blockIdx.x * 128, i0 = blockIdx.y * 128, b = blockIdx.z;

  for (int idx = t; idx < NH*128; idx += 256) {
    const int hh = idx >> 7, r = idx & 127;
    const float* p = ml + ((size_t)(b*NH + hh)*LSEQ + i0 + r)*2;
    mh[hh][r] = p[0];
    wh[hh][r] = (1.0f/NH) / p[1];
  }

  f32x16 acc[2][2], fin[2][2];
  #pragma unroll
  for (int i = 0; i < 2; ++i)
    #pragma unroll
    for (int j = 0; j < 2; ++j)
      #pragma unroll
      for (int r = 0; r < 16; ++r) { acc[i][j][r] = 0.f; fin[i][j][r] = 0.f; }

  const int lane = t & 63, wv = t >> 6, wm = wv >> 1, wn = wv & 1;
  const int rl = lane & 31, kq = lane >> 5;

  for (int kt = 0; kt < EMB/32; ++kt) {
    __syncthreads();
    #pragma unroll
    for (int c = 0; c < 2; ++c) {
      const int id = c*256 + t, row = id >> 2, kO = id & 3;
      const float* sa = qkv + (size_t)((i0+row)*BATCH + b)*E3 + kt*32 + kO*8;
      float4 a0 = *(const float4*)sa, a1 = *(const float4*)(sa+4);
      split_store(a0, a1, &sAh[kO*1056 + row*8], &sAl[kO*1056 + row*8]);
      const float* sb = qkv + (size_t)((j0+row)*BATCH + b)*E3 + EMB + kt*32 + kO*8;
      float4 b0 = *(const float4*)sb, b1 = *(const float4*)(sb+4);
      split_store(b0, b1, &sBh[kO*1056 + row*8], &sBl[kO*1056 + row*8]);
    }
    __syncthreads();
    #pragma unroll
    for (int s = 0; s < 2; ++s) {
      const int kO = s*2 + kq;
      const int ao = kO*1056 + (wm*64 + rl)*8;
      const int bo = kO*1056 + (wn*64 + rl)*8;
      short8 ah0 = *(const short8*)&sAh[ao];
      short8 ah1 = *(const short8*)&sAh[ao + 256];
      short8 al0 = *(const short8*)&sAl[ao];
      short8 al1 = *(const short8*)&sAl[ao + 256];
      short8 bh0 = *(const short8*)&sBh[bo];
      short8 bh1 = *(const short8*)&sBh[bo + 256];
      short8 bl0 = *(const short8*)&sBl[bo];
      short8 bl1 = *(const short8*)&sBl[bo + 256];
      MFMA32(acc[0][0], ah0, bh0); MFMA32(acc[0][1], ah0, bh1);
      MFMA32(acc[1][0], ah1, bh0); MFMA32(acc[1][1], ah1, bh1);
      MFMA32(acc[0][0], ah0, bl0); MFMA32(acc[0][1], ah0, bl1);
      MFMA32(acc[1][0], ah1, bl0); MFMA32(acc[1][1], ah1, bl1);
      MFMA32(acc[0][0], al0, bh0); MFMA32(acc[0][1], al0, bh1);
      MFMA32(acc[1][0], al1, bh0); MFMA32(acc[1][1], al1, bh1);
    }
    if (kt & 1) {
      const int hh = kt >> 1;
      #pragma unroll
      for (int fi = 0; fi < 2; ++fi)
        #pragma unroll
        for (int fj = 0; fj < 2; ++fj)
          #pragma unroll
          for (int reg = 0; reg < 16; ++reg) {
            const int rr = (reg & 3) + 8*(reg >> 2) + 4*(lane >> 5);
            const int row = wm*64 + fi*32 + rr;
            fin[fi][fj][reg] += __expf(acc[fi][fj][reg] - mh[hh][row]) * wh[hh][row];
            acc[fi][fj][reg] = 0.f;
          }
    }
  }

  #pragma unroll
  for (int fj = 0; fj < 2; ++fj) {
    const int j = j0 + wn*64 + fj*32 + rl;
    #pragma unroll
    for (int fi = 0; fi < 2; ++fi) {
      #pragma unroll
      for (int reg = 0; reg < 16; ++reg) {
        const int rr = (reg & 3) + 8*(reg >> 2) + 4*(lane >> 5);
        const int i = i0 + wm*64 + fi*32 + rr;
        attnW[((size_t)b*LSEQ + i)*LSEQ + j] = fin[fi][fj][reg];
      }
    }
  }
}

// ---------------------------------------------------------------------------
// gemm_lora: T = relu(A(M x 768) @ Wd(64 x 768)^T + db)  (unchanged)
// ---------------------------------------------------------------------------
__global__ __launch_bounds__(256) void gemm_lora(
    const float* __restrict__ A, const float* __restrict__ Wd,
    const float* __restrict__ db, float* __restrict__ T)
{
  __shared__ float As[16][36];
  __shared__ float Bs[16][68];
  const int tx = (int)threadIdx.x & 15, ty = (int)threadIdx.x >> 4;
  const int row0 = blockIdx.x * 32;
  float acc[2][4];
  #pragma unroll
  for (int i = 0; i < 2; ++i)
    #pragma unroll
    for (int j = 0; j < 4; ++j) acc[i][j] = 0.f;

  for (int k0 = 0; k0 < EMB; k0 += 16) {
    for (int idx = (int)threadIdx.x; idx < 32*4; idx += 256) {
      int r = idx >> 2, cq = idx & 3;
      float4 t4 = *(const float4*)(A + (size_t)(row0+r)*EMB + k0 + cq*4);
      As[cq*4+0][r]=t4.x; As[cq*4+1][r]=t4.y; As[cq*4+2][r]=t4.z; As[cq*4+3][r]=t4.w;
    }
    for (int idx = (int)threadIdx.x; idx < 64*4; idx += 256) {
      int r = idx >> 2, cq = idx & 3;
      float4 t4 = *(const float4*)(Wd + (size_t)r*EMB + k0 + cq*4);
      Bs[cq*4+0][r]=t4.x; Bs[cq*4+1][r]=t4.y; Bs[cq*4+2][r]=t4.z; Bs[cq*4+3][r]=t4.w;
    }
    __syncthreads();
    #pragma unroll
    for (int k = 0; k < 16; ++k) {
      float a0 = As[k][ty*2], a1 = As[k][ty*2+1];
      #pragma unroll
      for (int j = 0; j < 4; ++j) {
        float bb = Bs[k][tx*4+j];
        acc[0][j] = fmaf(a0, bb, acc[0][j]);
        acc[1][j] = fmaf(a1, bb, acc[1][j]);
      }
    }
    __syncthreads();
  }
  #pragma unroll
  for (int i = 0; i < 2; ++i) {
    const int r = row0 + ty*2 + i;
    #pragma unroll
    for (int j = 0; j < 4; ++j) {
      const int c = tx*4 + j;
      T[(size_t)r*RNK + c] = fmaxf(acc[i][j] + db[c], 0.f);
    }
  }
}

// ---------------------------------------------------------------------------
// flash_mfma: MFMA flash attention, swapped-operand structure.
//  grid (LSEQ/128, B, H), block 256 (4 waves), wave tile = 32 q-rows x 128 j.
//  S^T = K.Q^T via MFMA (Q in regs as B-frags) -> softmax lane-local (col =
//  lane&31 = q-row; one shfl_xor(32) merges the j-halves) -> P^T converted to
//  PV B-frags in-register via trunc-pack bf16 + permlane32_swap (T12) ->
//  O^T = V^T.P accumulated in regs (V^T staged transposed in LDS).
//  Split-bf16 hi/lo 3-pass on both MFMA stages => ~f32 accuracy.
// ---------------------------------------------------------------------------
__global__ __launch_bounds__(256, 2) void flash_mfma(
    const float* __restrict__ qkv, float* __restrict__ attnO,
    float* __restrict__ ml)
{
  // K planes: 8 kO-octs x (128 rows x 8 shorts + 8 pad) = 1032 shorts/oct
  __shared__ __align__(16) short    sKh[8*1032], sKl[8*1032];
  // V^T planes: 64 d-rows x 68 u32 (64 j-pairs + pad; 272B = odd 16B mult)
  __shared__ __align__(16) unsigned sVh[64*68], sVl[64*68];

  const int t  = (int)threadIdx.x;
  const int i0 = blockIdx.x * 128;
  const int b  = blockIdx.y, h = blockIdx.z;
  const int lane = t & 63, wv = t >> 6;
  const int rl = lane & 31, h5 = lane >> 5;

  // ---- Q B-fragments in registers (4 ksteps over d, hi+lo planes) ----
  short8 qh[4], ql[4];
  {
    const int qi = i0 + wv*32 + rl;
    const float* qp = qkv + ((size_t)qi*BATCH + b)*E3 + h*HD + h5*8;
    #pragma unroll
    for (int t4 = 0; t4 < 4; ++t4) {
      float4 f0 = *(const float4*)(qp + t4*16);
      float4 f1 = *(const float4*)(qp + t4*16 + 4);
      unsigned hh0,hh1,hh2,hh3, ll0,ll1,ll2,ll3;
      bsplit2(f0.x, f0.y, hh0, ll0);
      bsplit2(f0.z, f0.w, hh1, ll1);
      bsplit2(f1.x, f1.y, hh2, ll2);
      bsplit2(f1.z, f1.w, hh3, ll3);
      qh[t4] = pack4(hh0, hh1, hh2, hh3);
      ql[t4] = pack4(ll0, ll1, ll2, ll3);
    }
  }

  f32x16 ov[2];
  #pragma unroll
  for (int df = 0; df < 2; ++df)
    #pragma unroll
    for (int r = 0; r < 16; ++r) ov[df][r] = 0.f;
  float m = -3.0e38f, lsum = 0.f;

  for (int c = 0; c < LSEQ/128; ++c) {
    __syncthreads();
    // ---- stage K rows (j) x 64 d, split hi/lo ----
    #pragma unroll
    for (int it = 0; it < 4; ++it) {
      const int idx = it*256 + t, j = idx >> 3, kO = idx & 7;
      const float* src = qkv + ((size_t)(c*128 + j)*BATCH + b)*E3 + EMB + h*HD + kO*8;
      float4 f0 = *(const float4*)src, f1 = *(const float4*)(src+4);
      split_store(f0, f1, &sKh[kO*1032 + j*8], &sKl[kO*1032 + j*8]);
    }
    // ---- stage V transposed: VT[d][j-pair], split hi/lo ----
    {
      const int p = t & 63;
      #pragma unroll
      for (int it = 0; it < 4; ++it) {
        const int d4 = it*16 + (t >> 6)*4;
        const float* v0 = qkv + ((size_t)(c*128 + 2*p)*BATCH + b)*E3 + 2*EMB + h*HD + d4;
        const float* v1 = v0 + (size_t)BATCH*E3;
        float4 a = *(const float4*)v0, bb = *(const float4*)v1;
        unsigned hu, lu;
        bsplit2(a.x, bb.x, hu, lu); sVh[(d4+0)*68 + p] = hu; sVl[(d4+0)*68 + p] = lu;
        bsplit2(a.y, bb.y, hu, lu); sVh[(d4+1)*68 + p] = hu; sVl[(d4+1)*68 + p] = lu;
        bsplit2(a.z, bb.z, hu, lu); sVh[(d4+2)*68 + p] = hu; sVl[(d4+2)*68 + p] = lu;
        bsplit2(a.w, bb.w, hu, lu); sVh[(d4+3)*68 + p] = hu; sVl[(d4+3)*68 + p] = lu;
      }
    }
    __syncthreads();

    // ---- S^T = K . Q^T  (m = j, n = i; 3-pass split) ----
    f32x16 st[4];
    #pragma unroll
    for (int mf = 0; mf < 4; ++mf)
      #pragma unroll
      for (int r = 0; r < 16; ++r) st[mf][r] = 0.f;
    #pragma unroll
    for (int t4 = 0; t4 < 4; ++t4) {
      const int kO = t4*2 + h5;
      #pragma unroll
      for (int mf = 0; mf < 4; ++mf) {
        const int ao = kO*1032 + (mf*32 + rl)*8;
        short8 kh = *(const short8*)&sKh[ao];
        short8 kl = *(const short8*)&sKl[ao];
        MFMA32(st[mf], kh, qh[t4]);
        MFMA32(st[mf], kh, ql[t4]);
        MFMA32(st[mf], kl, qh[t4]);
      }
    }

    // ---- online softmax (lane-local + one cross-half shfl) ----
    float pm = st[0][0];
    #pragma unroll
    for (int mf = 0; mf < 4; ++mf)
      #pragma unroll
      for (int r = 0; r < 16; ++r) pm = fmaxf(pm, st[mf][r]);
    pm = fmaxf(pm, __shfl_xor(pm, 32));
    const float mnew = fmaxf(m, pm);
    const float al = __expf(m - mnew);
    float rs = 0.f;
    #pragma unroll
    for (int mf = 0; mf < 4; ++mf)
      #pragma unroll
      for (int r = 0; r < 16; ++r) {
        float p = __expf(st[mf][r] - mnew);
        st[mf][r] = p;
        rs += p;
      }
    rs += __shfl_xor(rs, 32);
    lsum = lsum*al + rs;
    m = mnew;
    #pragma unroll
    for (int df = 0; df < 2; ++df)
      #pragma unroll
      for (int r = 0; r < 16; ++r) ov[df][r] *= al;

    // ---- PV: O^T += V^T . P  (P B-frags built in-register) ----
    #pragma unroll
    for (int f = 0; f < 4; ++f) {
      #pragma unroll
      for (int u = 0; u < 2; ++u) {
        const float p0 = st[f][8*u+0], p1 = st[f][8*u+1];
        const float p2 = st[f][8*u+2], p3 = st[f][8*u+3];
        const float p4 = st[f][8*u+4], p5 = st[f][8*u+5];
        const float p6 = st[f][8*u+6], p7 = st[f][8*u+7];
        unsigned a0 = pkhi(p0,p1), a1 = pkhi(p2,p3);
        unsigned b0 = pkhi(p4,p5), b1 = pkhi(p6,p7);
        unsigned c0 = pkhi(p0-hif(p0), p1-hif(p1));
        unsigned c1 = pkhi(p2-hif(p2), p3-hif(p3));
        unsigned d0 = pkhi(p4-hif(p4), p5-hif(p5));
        unsigned d1 = pkhi(p6-hif(p6), p7-hif(p7));
        int2v r0 = __builtin_amdgcn_permlane32_swap((int)a0, (int)b0, false, false);
        int2v r1 = __builtin_amdgcn_permlane32_swap((int)a1, (int)b1, false, false);
        int2v r2 = __builtin_amdgcn_permlane32_swap((int)c0, (int)d0, false, false);
        int2v r3 = __builtin_amdgcn_permlane32_swap((int)c1, (int)d1, false, false);
        short8 ph = pack4((unsigned)r0.x, (unsigned)r1.x, (unsigned)r0.y, (unsigned)r1.y);
        short8 pl = pack4((unsigned)r2.x, (unsigned)r3.x, (unsigned)r2.y, (unsigned)r3.y);
        const int tt = f*2 + u;
        #pragma unroll
        for (int df = 0; df < 2; ++df) {
          const int vo = (df*32 + rl)*68 + tt*8 + h5*4;
          short8 vh = *(const short8*)&sVh[vo];
          short8 vl = *(const short8*)&sVl[vo];
          MFMA32(ov[df], vh, ph);
          MFMA32(ov[df], vh, pl);
          MFMA32(ov[df], vl, ph);
        }
      }
    }
  }

  // ---- epilogue: normalize, write attnO and (m,l) ----
  const float inv = 1.f / lsum;
  const int qi = i0 + wv*32 + rl;
  #pragma unroll
  for (int df = 0; df < 2; ++df) {
    #pragma unroll
    for (int g = 0; g < 4; ++g) {
      const int dbase = df*32 + 8*g + 4*h5;
      float4 o = make_float4(ov[df][4*g+0]*inv, ov[df][4*g+1]*inv,
                             ov[df][4*g+2]*inv, ov[df][4*g+3]*inv);
      *(float4*)(attnO + ((size_t)qi*BATCH + b)*EMB + h*HD + dbase) = o;
    }
  }
  if (h5 == 0) {
    const size_t base = ((size_t)(b*NH + h)*LSEQ + qi)*2;
    ml[base]   = m;
    ml[base+1] = lsum;
  }
}

// ---------------------------------------------------------------------------
extern "C" void kernel_launch(void* const* d_in, const int* in_sizes, int n_in,
                              void* d_out, int out_size, void* d_ws, size_t ws_size,
                              hipStream_t stream) {
  (void)in_sizes; (void)n_in; (void)out_size; (void)ws_size;
  const float* query     = (const float*)d_in[0];
  const float* in_proj_w = (const float*)d_in[3];
  const float* in_proj_b = (const float*)d_in[4];
  const float* s1        = (const float*)d_in[5];
  const float* sh1       = (const float*)d_in[6];
  const float* s2        = (const float*)d_in[7];
  const float* sh2       = (const float*)d_in[8];
  const float* out_w     = (const float*)d_in[9];
  const float* out_b     = (const float*)d_in[10];
  const float* l1_dw     = (const float*)d_in[11];
  const float* l1_db     = (const float*)d_in[12];
  const float* l1_uw     = (const float*)d_in[13];
  const float* l1_ub     = (const float*)d_in[14];
  const float* l1_s      = (const float*)d_in[15];
  const float* l2_dw     = (const float*)d_in[16];
  const float* l2_db     = (const float*)d_in[17];
  const float* l2_uw     = (const float*)d_in[18];
  const float* l2_ub     = (const float*)d_in[19];
  const float* l2_s      = (const float*)d_in[20];

  float* out2  = (float*)d_out;                      // (L,B,E)
  float* attnW = out2 + (size_t)LSEQ*BATCH*EMB;      // (B,L,L)

  // Workspace (f32, ~65MB -- unchanged layout)
  float* ws   = (float*)d_ws;
  float* qkv  = ws;                                  // LB*E3  = 9,437,184
  float* t1   = qkv  + (size_t)LB*E3;                // LB*RNK =   262,144
  float* attn = t1   + (size_t)LB*RNK;               // LB*EMB = 3,145,728
  float* out1 = attn + (size_t)LB*EMB;               // LB*EMB = 3,145,728
  float* t2   = out1 + (size_t)LB*EMB;               // LB*RNK =   262,144
  float* ml   = t1;  // (B,NH,LSEQ,2); t1 dead after qkv GEMM, before flash

  // t1 = relu(query @ l1_dw^T + l1_db)
  gemm_lora<<<dim3(LB/32), dim3(256), 0, stream>>>(query, l1_dw, l1_db, t1);

  // qkv = ssf1(query@W^T + b) + (t1@l1_uw^T + l1_ub)*l1_s ; cols<768 scaled 0.125
  gemm_mfma<true><<<dim3(LB/128, E3/128), dim3(256), 0, stream>>>(
      query, in_proj_w, s1, 1, t1, l1_uw,
      in_proj_b, s1, sh1, l1_ub, l1_s, 1, qkv, E3, EMB);

  // attention output + per-row (m,l) stats  [ml aliases t1: t1 consumed above]
  flash_mfma<<<dim3(LSEQ/128, BATCH, NH), dim3(256), 0, stream>>>(qkv, attn, ml);

  // attn_weights = mean over heads (segmented MFMA GEMM, write-once)
  attnw_mfma<<<dim3(LSEQ/128, LSEQ/128, BATCH), dim3(256), 0, stream>>>(qkv, ml, attnW);

  // out1 = attn @ out_w^T + out_b
  gemm_mfma<false><<<dim3(LB/128, EMB/128), dim3(256), 0, stream>>>(
      attn, out_w, nullptr, 0, nullptr, nullptr,
      out_b, nullptr, nullptr, nullptr, nullptr, 0, out1, EMB, EMB);

  // t2 = relu(out1 @ l2_dw^T + l2_db)
  gemm_lora<<<dim3(LB/32), dim3(256), 0, stream>>>(out1, l2_dw, l2_db, t2);

  // out2 = ssf2(out1@out_w^T + out_b) + (t2@l2_uw^T + l2_ub)*l2_s
  gemm_mfma<true><<<dim3(LB/128, EMB/128), dim3(256), 0, stream>>>(
      out1, out_w, s2, 0, t2, l2_uw,
      out_b, s2, sh2, l2_ub, l2_s, 0, out2, EMB, EMB);
}

// Round 5
// 440.462 us; speedup vs baseline: 5.2938x; 1.2713x over previous
//
#include <hip/hip_runtime.h>

// Problem constants (L,B,E,H,R) = (2048, 2, 768, 12, 64)
#define LSEQ 2048
#define BATCH 2
#define EMB 768
#define NH 12
#define HD 64
#define RNK 64
#define E3 2304            // 3*EMB
#define LB (LSEQ*BATCH)    // 4096 rows, row index r = i*BATCH + b

typedef short short8 __attribute__((ext_vector_type(8)));
typedef float f32x16 __attribute__((ext_vector_type(16)));
typedef int   int4v  __attribute__((ext_vector_type(4)));
typedef int   int2v  __attribute__((ext_vector_type(2)));

#define MFMA32(acc, a, b) acc = __builtin_amdgcn_mfma_f32_32x32x16_bf16(a, b, acc, 0, 0, 0)

// split two f32 into packed bf16 hi (truncate) + bf16 lo (truncate of residual)
__device__ __forceinline__ void bsplit2(float x0, float x1, unsigned& hp, unsigned& lp) {
  unsigned u0 = __float_as_uint(x0), u1 = __float_as_uint(x1);
  hp = (u0 >> 16) | (u1 & 0xffff0000u);
  float l0 = x0 - __uint_as_float(u0 & 0xffff0000u);
  float l1 = x1 - __uint_as_float(u1 & 0xffff0000u);
  lp = (__float_as_uint(l0) >> 16) | (__float_as_uint(l1) & 0xffff0000u);
}
__device__ __forceinline__ unsigned pkhi(float a, float b) {
  return (__float_as_uint(a) >> 16) | (__float_as_uint(b) & 0xffff0000u);
}
__device__ __forceinline__ float hif(float a) {
  return __uint_as_float(__float_as_uint(a) & 0xffff0000u);
}
__device__ __forceinline__ short8 pack4(unsigned a, unsigned b, unsigned c, unsigned d) {
  int4v v = {(int)a, (int)b, (int)c, (int)d};
  return __builtin_bit_cast(short8, v);
}
// split one f32 into (hi short, lo short)
__device__ __forceinline__ void split1(float v, short& hs, short& ls) {
  unsigned uv = __float_as_uint(v);
  hs = (short)(uv >> 16);
  ls = (short)(__float_as_uint(v - __uint_as_float(uv & 0xffff0000u)) >> 16);
}

// 2D XCD-cluster swizzle: 8 XCDs as 4 row-groups x 2 col-groups.
// Requires RB%4==0 and CB%2==0.
__device__ __forceinline__ void xcd_map(int id, int RB, int CB, int& rb, int& cb) {
  const int xcd = id & 7, local = id >> 3;
  const int rq = RB >> 2, ch = CB >> 1;
  rb = (xcd & 3)*rq + (local % rq);
  cb = (xcd >> 2)*ch + (local / rq);
}

// ---------------------------------------------------------------------------
// convert_all: one pass splitting query + all (scale-folded) weights into
// hi/lo bf16 planes. 786432 chunks of 8 elements, exact grid.
//   seg0 query            -> qry planes            (scale 1)
//   seg1 in_proj_w        -> w1 planes  (s1[n], 0.125 for n<768)
//   seg2 l1_uw            -> u1 planes  (l1_s, 0.125 for n<768)
//   seg3 out_w            -> wo planes
//   seg4 out_w            -> wo2 planes (s2[n])
//   seg5 l2_uw            -> u2 planes  (l2_s)
// ---------------------------------------------------------------------------
__global__ __launch_bounds__(256) void convert_all(
    const float* __restrict__ q,  const float* __restrict__ w1,
    const float* __restrict__ s1, const float* __restrict__ uw1,
    const float* __restrict__ l1s, const float* __restrict__ wo,
    const float* __restrict__ s2, const float* __restrict__ uw2,
    const float* __restrict__ l2s,
    short* __restrict__ qh,  short* __restrict__ ql,
    short* __restrict__ w1h, short* __restrict__ w1l,
    short* __restrict__ u1h, short* __restrict__ u1l,
    short* __restrict__ woh, short* __restrict__ wol,
    short* __restrict__ wo2h, short* __restrict__ wo2l,
    short* __restrict__ u2h, short* __restrict__ u2l)
{
  const int idx = blockIdx.x*256 + (int)threadIdx.x;   // < 786432 exact
  const float* src; short *dh, *dl; float sc = 1.f; int e8;
  if (idx < 393216)      { e8 = idx;          src = q;   dh = qh;   dl = ql; }
  else if (idx < 614400) { e8 = idx - 393216; src = w1;  dh = w1h;  dl = w1l;
                           int n = e8/96; sc = s1[n]*(n < EMB ? 0.125f : 1.f); }
  else if (idx < 632832) { e8 = idx - 614400; src = uw1; dh = u1h;  dl = u1l;
                           int n = e8/8;  sc = l1s[0]*(n < EMB ? 0.125f : 1.f); }
  else if (idx < 706560) { e8 = idx - 632832; src = wo;  dh = woh;  dl = wol; }
  else if (idx < 780288) { e8 = idx - 706560; src = wo;  dh = wo2h; dl = wo2l;
                           sc = s2[e8/96]; }
  else                   { e8 = idx - 780288; src = uw2; dh = u2h;  dl = u2l;
                           sc = l2s[0]; }
  float4 f0 = *(const float4*)(src + (size_t)e8*8);
  float4 f1 = *(const float4*)(src + (size_t)e8*8 + 4);
  f0.x*=sc; f0.y*=sc; f0.z*=sc; f0.w*=sc;
  f1.x*=sc; f1.y*=sc; f1.z*=sc; f1.w*=sc;
  unsigned h0,h1,h2,h3, l0,l1,l2,l3;
  bsplit2(f0.x, f0.y, h0, l0);
  bsplit2(f0.z, f0.w, h1, l1);
  bsplit2(f1.x, f1.y, h2, l2);
  bsplit2(f1.z, f1.w, h3, l3);
  *(int4v*)(dh + (size_t)e8*8) = (int4v){(int)h0,(int)h1,(int)h2,(int)h3};
  *(int4v*)(dl + (size_t)e8*8) = (int4v){(int)l0,(int)l1,(int)l2,(int)l3};
}

// ---------------------------------------------------------------------------
// gemm_p: plane-fed split-bf16 3-pass MFMA GEMM.  C = A @ Weff^T + cc[c]
//  A planes [M][K], W planes [N][K] (all scales pre-folded into planes).
//  LORA: extra K=64 segment from A2/W2 planes.
//  cc[c] = bias*scale+shift + ub*ls, times 0.125 for c<768 if cqsc.
//  EPI 0: f32 only.  EPI 1: f32 + hi/lo planes (same [r][N] layout).
//  EPI 2: qkv scatter -> qp/kp [b][i][768] planes + vt [b][h][d][j] planes.
//  128x128 tile, BK=32, 4 waves of 64x64. 1D grid with 2D XCD clustering.
// ---------------------------------------------------------------------------
template<int EPI, bool LORA>
__global__ __launch_bounds__(256, 1) void gemm_p(
    const short* __restrict__ Ah, const short* __restrict__ Al,
    const short* __restrict__ Wh, const short* __restrict__ Wl,
    const short* __restrict__ A2h, const short* __restrict__ A2l,
    const short* __restrict__ W2h, const short* __restrict__ W2l,
    const float* __restrict__ bias, const float* __restrict__ scale,
    const float* __restrict__ shift, const float* __restrict__ ub,
    const float* __restrict__ lsp, int cqsc,
    float* __restrict__ Cf, short* __restrict__ Cph, short* __restrict__ Cpl,
    short* __restrict__ qph, short* __restrict__ qpl,
    short* __restrict__ kph, short* __restrict__ kpl,
    short* __restrict__ vth, short* __restrict__ vtl,
    int N, int K, int RB, int CB)
{
  __shared__ __align__(16) short sAh[4224], sAl[4224], sBh[4224], sBl[4224];
  const int t = (int)threadIdx.x;
  int rb, cb; xcd_map((int)blockIdx.x, RB, CB, rb, cb);
  const int row0 = rb*128, col0 = cb*128;
  const float lsv = LORA ? lsp[0] : 0.f;
  const int mainSteps = K >> 5;
  const int totSteps = mainSteps + (LORA ? 2 : 0);

  f32x16 acc[2][2];
  #pragma unroll
  for (int i = 0; i < 2; ++i)
    #pragma unroll
    for (int j = 0; j < 2; ++j)
      #pragma unroll
      for (int r = 0; r < 16; ++r) acc[i][j][r] = 0.f;

  const int lane = t & 63, wv = t >> 6, wm = wv >> 1, wn = wv & 1;
  const int rl = lane & 31, kq = lane >> 5;

  for (int kt = 0; kt < totSteps; ++kt) {
    const bool mn = (kt < mainSteps);
    const int kk = mn ? kt*32 : (kt - mainSteps)*32;
    __syncthreads();
    #pragma unroll
    for (int c = 0; c < 2; ++c) {
      const int id = c*256 + t, row = id >> 2, kO = id & 3;
      const int lds = kO*1056 + row*8;
      if (mn) {
        const size_t offA = (size_t)(row0+row)*K + kk + kO*8;
        *(int4v*)&sAh[lds] = *(const int4v*)(Ah + offA);
        *(int4v*)&sAl[lds] = *(const int4v*)(Al + offA);
        const size_t offB = (size_t)(col0+row)*K + kk + kO*8;
        *(int4v*)&sBh[lds] = *(const int4v*)(Wh + offB);
        *(int4v*)&sBl[lds] = *(const int4v*)(Wl + offB);
      } else {
        const size_t offA = (size_t)(row0+row)*RNK + kk + kO*8;
        *(int4v*)&sAh[lds] = *(const int4v*)(A2h + offA);
        *(int4v*)&sAl[lds] = *(const int4v*)(A2l + offA);
        const size_t offB = (size_t)(col0+row)*RNK + kk + kO*8;
        *(int4v*)&sBh[lds] = *(const int4v*)(W2h + offB);
        *(int4v*)&sBl[lds] = *(const int4v*)(W2l + offB);
      }
    }
    __syncthreads();
    #pragma unroll
    for (int s = 0; s < 2; ++s) {
      const int kO = s*2 + kq;
      const int ao = kO*1056 + (wm*64 + rl)*8;
      const int bo = kO*1056 + (wn*64 + rl)*8;
      short8 ah0 = *(const short8*)&sAh[ao];
      short8 ah1 = *(const short8*)&sAh[ao + 256];
      short8 al0 = *(const short8*)&sAl[ao];
      short8 al1 = *(const short8*)&sAl[ao + 256];
      short8 bh0 = *(const short8*)&sBh[bo];
      short8 bh1 = *(const short8*)&sBh[bo + 256];
      short8 bl0 = *(const short8*)&sBl[bo];
      short8 bl1 = *(const short8*)&sBl[bo + 256];
      MFMA32(acc[0][0], ah0, bh0); MFMA32(acc[0][1], ah0, bh1);
      MFMA32(acc[1][0], ah1, bh0); MFMA32(acc[1][1], ah1, bh1);
      MFMA32(acc[0][0], ah0, bl0); MFMA32(acc[0][1], ah0, bl1);
      MFMA32(acc[1][0], ah1, bl0); MFMA32(acc[1][1], ah1, bl1);
      MFMA32(acc[0][0], al0, bh0); MFMA32(acc[0][1], al0, bh1);
      MFMA32(acc[1][0], al1, bh0); MFMA32(acc[1][1], al1, bh1);
    }
  }

  // epilogue (C/D map: col=lane&31, row=(reg&3)+8*(reg>>2)+4*(lane>>5))
  #pragma unroll
  for (int fj = 0; fj < 2; ++fj) {
    const int c = col0 + wn*64 + fj*32 + rl;
    float ccv = bias ? bias[c] : 0.f;
    if (scale) ccv = ccv*scale[c] + shift[c];
    if (ub)    ccv += ub[c]*lsv;
    if (cqsc && c < EMB) ccv *= 0.125f;
    #pragma unroll
    for (int fi = 0; fi < 2; ++fi) {
      #pragma unroll
      for (int reg = 0; reg < 16; ++reg) {
        const int rr = (reg & 3) + 8*(reg >> 2) + 4*(lane >> 5);
        const int r = row0 + wm*64 + fi*32 + rr;
        const float v = acc[fi][fj][reg] + ccv;
        if constexpr (EPI == 0) {
          Cf[(size_t)r*N + c] = v;
        } else if constexpr (EPI == 1) {
          Cf[(size_t)r*N + c] = v;
          short hs, ls; split1(v, hs, ls);
          Cph[(size_t)r*N + c] = hs;
          Cpl[(size_t)r*N + c] = ls;
        } else {
          const int bb = r & 1, ii = r >> 1;
          short hs, ls; split1(v, hs, ls);
          if (c < EMB) {
            const size_t o = ((size_t)bb*LSEQ + ii)*EMB + c;
            qph[o] = hs; qpl[o] = ls;
          } else if (c < 2*EMB) {
            const size_t o = ((size_t)bb*LSEQ + ii)*EMB + (c - EMB);
            kph[o] = hs; kpl[o] = ls;
          } else {
            const int hh = (c - 2*EMB) >> 6, dd = (c - 2*EMB) & 63;
            const size_t o = (((size_t)bb*NH + hh)*HD + dd)*LSEQ + ii;
            vth[o] = hs; vtl[o] = ls;
          }
        }
      }
    }
  }
}

// ---------------------------------------------------------------------------
// attnw_p: attn_weights via segmented K=768 plane-fed 3-pass MFMA GEMM.
// A = q planes rows (b,i), B = k planes rows (b,j); fold exp after each head.
// ---------------------------------------------------------------------------
__global__ __launch_bounds__(256, 1) void attnw_p(
    const short* __restrict__ qph, const short* __restrict__ qpl,
    const short* __restrict__ kph, const short* __restrict__ kpl,
    const float* __restrict__ ml, float* __restrict__ attnW)
{
  __shared__ __align__(16) short sAh[4224], sAl[4224], sBh[4224], sBl[4224];
  __shared__ float mh[NH][128], wh[NH][128];
  const int t = (int)threadIdx.x;
  int jb, ib; xcd_map((int)blockIdx.x, 16, 16, jb, ib);
  const int j0 = jb*128, i0 = ib*128, b = blockIdx.z;

  for (int idx = t; idx < NH*128; idx += 256) {
    const int hh = idx >> 7, r = idx & 127;
    const float* p = ml + ((size_t)(b*NH + hh)*LSEQ + i0 + r)*2;
    mh[hh][r] = p[0];
    wh[hh][r] = (1.0f/NH) / p[1];
  }

  f32x16 acc[2][2], fin[2][2];
  #pragma unroll
  for (int i = 0; i < 2; ++i)
    #pragma unroll
    for (int j = 0; j < 2; ++j)
      #pragma unroll
      for (int r = 0; r < 16; ++r) { acc[i][j][r] = 0.f; fin[i][j][r] = 0.f; }

  const int lane = t & 63, wv = t >> 6, wm = wv >> 1, wn = wv & 1;
  const int rl = lane & 31, kq = lane >> 5;
  const size_t abase = ((size_t)b*LSEQ + i0)*EMB;
  const size_t bbase = ((size_t)b*LSEQ + j0)*EMB;

  for (int kt = 0; kt < EMB/32; ++kt) {
    __syncthreads();   // also covers mh/wh staging on kt==0
    #pragma unroll
    for (int c = 0; c < 2; ++c) {
      const int id = c*256 + t, row = id >> 2, kO = id & 3;
      const int lds = kO*1056 + row*8;
      const size_t offA = abase + (size_t)row*EMB + kt*32 + kO*8;
      *(int4v*)&sAh[lds] = *(const int4v*)(qph + offA);
      *(int4v*)&sAl[lds] = *(const int4v*)(qpl + offA);
      const size_t offB = bbase + (size_t)row*EMB + kt*32 + kO*8;
      *(int4v*)&sBh[lds] = *(const int4v*)(kph + offB);
      *(int4v*)&sBl[lds] = *(const int4v*)(kpl + offB);
    }
    __syncthreads();
    #pragma unroll
    for (int s = 0; s < 2; ++s) {
      const int kO = s*2 + kq;
      const int ao = kO*1056 + (wm*64 + rl)*8;
      const int bo = kO*1056 + (wn*64 + rl)*8;
      short8 ah0 = *(const short8*)&sAh[ao];
      short8 ah1 = *(const short8*)&sAh[ao + 256];
      short8 al0 = *(const short8*)&sAl[ao];
      short8 al1 = *(const short8*)&sAl[ao + 256];
      short8 bh0 = *(const short8*)&sBh[bo];
      short8 bh1 = *(const short8*)&sBh[bo + 256];
      short8 bl0 = *(const short8*)&sBl[bo];
      short8 bl1 = *(const short8*)&sBl[bo + 256];
      MFMA32(acc[0][0], ah0, bh0); MFMA32(acc[0][1], ah0, bh1);
      MFMA32(acc[1][0], ah1, bh0); MFMA32(acc[1][1], ah1, bh1);
      MFMA32(acc[0][0], ah0, bl0); MFMA32(acc[0][1], ah0, bl1);
      MFMA32(acc[1][0], ah1, bl0); MFMA32(acc[1][1], ah1, bl1);
      MFMA32(acc[0][0], al0, bh0); MFMA32(acc[0][1], al0, bh1);
      MFMA32(acc[1][0], al1, bh0); MFMA32(acc[1][1], al1, bh1);
    }
    if (kt & 1) {                      // completed head segment
      const int hh = kt >> 1;
      #pragma unroll
      for (int fi = 0; fi < 2; ++fi)
        #pragma unroll
        for (int fj = 0; fj < 2; ++fj)
          #pragma unroll
          for (int reg = 0; reg < 16; ++reg) {
            const int rr = (reg & 3) + 8*(reg >> 2) + 4*(lane >> 5);
            const int row = wm*64 + fi*32 + rr;
            fin[fi][fj][reg] += __expf(acc[fi][fj][reg] - mh[hh][row]) * wh[hh][row];
            acc[fi][fj][reg] = 0.f;
          }
    }
  }

  #pragma unroll
  for (int fj = 0; fj < 2; ++fj) {
    const int j = j0 + wn*64 + fj*32 + rl;
    #pragma unroll
    for (int fi = 0; fi < 2; ++fi) {
      #pragma unroll
      for (int reg = 0; reg < 16; ++reg) {
        const int rr = (reg & 3) + 8*(reg >> 2) + 4*(lane >> 5);
        const int i = i0 + wm*64 + fi*32 + rr;
        attnW[((size_t)b*LSEQ + i)*LSEQ + j] = fin[fi][fj][reg];
      }
    }
  }
}

// ---------------------------------------------------------------------------
// gemm_lora: T = relu(A(M x 768) @ Wd(64 x 768)^T + db) -> hi/lo planes
// ---------------------------------------------------------------------------
__global__ __launch_bounds__(256) void gemm_lora(
    const float* __restrict__ A, const float* __restrict__ Wd,
    const float* __restrict__ db,
    short* __restrict__ Th, short* __restrict__ Tl)
{
  __shared__ float As[16][36];
  __shared__ float Bs[16][68];
  const int tx = (int)threadIdx.x & 15, ty = (int)threadIdx.x >> 4;
  const int row0 = blockIdx.x * 32;
  float acc[2][4];
  #pragma unroll
  for (int i = 0; i < 2; ++i)
    #pragma unroll
    for (int j = 0; j < 4; ++j) acc[i][j] = 0.f;

  for (int k0 = 0; k0 < EMB; k0 += 16) {
    for (int idx = (int)threadIdx.x; idx < 32*4; idx += 256) {
      int r = idx >> 2, cq = idx & 3;
      float4 t4 = *(const float4*)(A + (size_t)(row0+r)*EMB + k0 + cq*4);
      As[cq*4+0][r]=t4.x; As[cq*4+1][r]=t4.y; As[cq*4+2][r]=t4.z; As[cq*4+3][r]=t4.w;
    }
    for (int idx = (int)threadIdx.x; idx < 64*4; idx += 256) {
      int r = idx >> 2, cq = idx & 3;
      float4 t4 = *(const float4*)(Wd + (size_t)r*EMB + k0 + cq*4);
      Bs[cq*4+0][r]=t4.x; Bs[cq*4+1][r]=t4.y; Bs[cq*4+2][r]=t4.z; Bs[cq*4+3][r]=t4.w;
    }
    __syncthreads();
    #pragma unroll
    for (int k = 0; k < 16; ++k) {
      float a0 = As[k][ty*2], a1 = As[k][ty*2+1];
      #pragma unroll
      for (int j = 0; j < 4; ++j) {
        float bb = Bs[k][tx*4+j];
        acc[0][j] = fmaf(a0, bb, acc[0][j]);
        acc[1][j] = fmaf(a1, bb, acc[1][j]);
      }
    }
    __syncthreads();
  }
  #pragma unroll
  for (int i = 0; i < 2; ++i) {
    const int r = row0 + ty*2 + i;
    #pragma unroll
    for (int j = 0; j < 4; ++j) {
      const int c = tx*4 + j;
      float v = fmaxf(acc[i][j] + db[c], 0.f);
      short hs, ls; split1(v, hs, ls);
      Th[(size_t)r*RNK + c] = hs;
      Tl[(size_t)r*RNK + c] = ls;
    }
  }
}

// ---------------------------------------------------------------------------
// flash_p: plane-fed MFMA flash attention (swapped-operand, as round 4).
//  Q frags loaded directly from q planes; K staged from k planes; V^T staged
//  from pre-transposed vt planes (contiguous 256B rows). No split math.
//  Writes attn output as hi/lo planes (ap) + per-row (m,l).
// ---------------------------------------------------------------------------
__global__ __launch_bounds__(256, 2) void flash_p(
    const short* __restrict__ qph, const short* __restrict__ qpl,
    const short* __restrict__ kph, const short* __restrict__ kpl,
    const short* __restrict__ vth, const short* __restrict__ vtl,
    short* __restrict__ aph, short* __restrict__ apl,
    float* __restrict__ ml)
{
  __shared__ __align__(16) short    sKh[8*1032], sKl[8*1032];
  __shared__ __align__(16) unsigned sVh[64*68], sVl[64*68];

  const int t  = (int)threadIdx.x;
  const int i0 = blockIdx.x * 128;
  const int b  = blockIdx.y, h = blockIdx.z;
  const int lane = t & 63, wv = t >> 6;
  const int rl = lane & 31, h5 = lane >> 5;

  // Q B-fragments straight from planes
  short8 qh[4], ql[4];
  {
    const int qi = i0 + wv*32 + rl;
    const size_t qo = ((size_t)b*LSEQ + qi)*EMB + h*HD + h5*8;
    #pragma unroll
    for (int t4 = 0; t4 < 4; ++t4) {
      qh[t4] = *(const short8*)(qph + qo + t4*16);
      ql[t4] = *(const short8*)(qpl + qo + t4*16);
    }
  }

  f32x16 ov[2];
  #pragma unroll
  for (int df = 0; df < 2; ++df)
    #pragma unroll
    for (int r = 0; r < 16; ++r) ov[df][r] = 0.f;
  float m = -3.0e38f, lsum = 0.f;

  const size_t kb0 = (size_t)b*LSEQ*EMB + h*HD;
  const size_t vb0 = ((size_t)b*NH + h)*HD*LSEQ;

  for (int c = 0; c < LSEQ/128; ++c) {
    __syncthreads();
    // stage K: 128 j x 64 d, hi/lo (8 lanes cover one full 128B row)
    #pragma unroll
    for (int it = 0; it < 4; ++it) {
      const int id = it*256 + t, j = id >> 3, kO = id & 7;
      const size_t off = kb0 + (size_t)(c*128 + j)*EMB + kO*8;
      const int lds = kO*1032 + j*8;
      *(int4v*)&sKh[lds] = *(const int4v*)(kph + off);
      *(int4v*)&sKl[lds] = *(const int4v*)(kpl + off);
    }
    // stage V^T: 64 d x 128 j from contiguous vt rows
    #pragma unroll
    for (int it = 0; it < 4; ++it) {
      const int id = it*256 + t, d = id >> 4, ch = id & 15;
      const size_t off = vb0 + (size_t)d*LSEQ + c*128 + ch*8;
      const int lds = d*68 + ch*4;
      *(int4v*)&sVh[lds] = *(const int4v*)(vth + off);
      *(int4v*)&sVl[lds] = *(const int4v*)(vtl + off);
    }
    __syncthreads();

    // S^T = K . Q^T (3-pass split)
    f32x16 st[4];
    #pragma unroll
    for (int mf = 0; mf < 4; ++mf)
      #pragma unroll
      for (int r = 0; r < 16; ++r) st[mf][r] = 0.f;
    #pragma unroll
    for (int t4 = 0; t4 < 4; ++t4) {
      const int kO = t4*2 + h5;
      #pragma unroll
      for (int mf = 0; mf < 4; ++mf) {
        const int ao = kO*1032 + (mf*32 + rl)*8;
        short8 kh = *(const short8*)&sKh[ao];
        short8 kl = *(const short8*)&sKl[ao];
        MFMA32(st[mf], kh, qh[t4]);
        MFMA32(st[mf], kh, ql[t4]);
        MFMA32(st[mf], kl, qh[t4]);
      }
    }

    // online softmax (lane-local + one cross-half shfl)
    float pm = st[0][0];
    #pragma unroll
    for (int mf = 0; mf < 4; ++mf)
      #pragma unroll
      for (int r = 0; r < 16; ++r) pm = fmaxf(pm, st[mf][r]);
    pm = fmaxf(pm, __shfl_xor(pm, 32));
    const float mnew = fmaxf(m, pm);
    const float al = __expf(m - mnew);
    float rs = 0.f;
    #pragma unroll
    for (int mf = 0; mf < 4; ++mf)
      #pragma unroll
      for (int r = 0; r < 16; ++r) {
        float p = __expf(st[mf][r] - mnew);
        st[mf][r] = p;
        rs += p;
      }
    rs += __shfl_xor(rs, 32);
    lsum = lsum*al + rs;
    m = mnew;
    #pragma unroll
    for (int df = 0; df < 2; ++df)
      #pragma unroll
      for (int r = 0; r < 16; ++r) ov[df][r] *= al;

    // PV: O^T += V^T . P (P B-frags built in-register via permlane swap)
    #pragma unroll
    for (int f = 0; f < 4; ++f) {
      #pragma unroll
      for (int u = 0; u < 2; ++u) {
        const float p0 = st[f][8*u+0], p1 = st[f][8*u+1];
        const float p2 = st[f][8*u+2], p3 = st[f][8*u+3];
        const float p4 = st[f][8*u+4], p5 = st[f][8*u+5];
        const float p6 = st[f][8*u+6], p7 = st[f][8*u+7];
        unsigned a0 = pkhi(p0,p1), a1 = pkhi(p2,p3);
        unsigned b0 = pkhi(p4,p5), b1 = pkhi(p6,p7);
        unsigned c0 = pkhi(p0-hif(p0), p1-hif(p1));
        unsigned c1 = pkhi(p2-hif(p2), p3-hif(p3));
        unsigned d0 = pkhi(p4-hif(p4), p5-hif(p5));
        unsigned d1 = pkhi(p6-hif(p6), p7-hif(p7));
        int2v r0 = __builtin_amdgcn_permlane32_swap((int)a0, (int)b0, false, false);
        int2v r1 = __builtin_amdgcn_permlane32_swap((int)a1, (int)b1, false, false);
        int2v r2 = __builtin_amdgcn_permlane32_swap((int)c0, (int)d0, false, false);
        int2v r3 = __builtin_amdgcn_permlane32_swap((int)c1, (int)d1, false, false);
        short8 ph = pack4((unsigned)r0.x, (unsigned)r1.x, (unsigned)r0.y, (unsigned)r1.y);
        short8 pl = pack4((unsigned)r2.x, (unsigned)r3.x, (unsigned)r2.y, (unsigned)r3.y);
        const int tt = f*2 + u;
        #pragma unroll
        for (int df = 0; df < 2; ++df) {
          const int vo = (df*32 + rl)*68 + tt*8 + h5*4;
          short8 vh = *(const short8*)&sVh[vo];
          short8 vl = *(const short8*)&sVl[vo];
          MFMA32(ov[df], vh, ph);
          MFMA32(ov[df], vh, pl);
          MFMA32(ov[df], vl, ph);
        }
      }
    }
  }

  // epilogue: normalize, write attn output planes and (m,l)
  const float inv = 1.f / lsum;
  const int qi = i0 + wv*32 + rl;
  const size_t ao = ((size_t)qi*BATCH + b)*EMB + h*HD;
  #pragma unroll
  for (int df = 0; df < 2; ++df) {
    #pragma unroll
    for (int g = 0; g < 4; ++g) {
      const int dbase = df*32 + 8*g + 4*h5;
      #pragma unroll
      for (int u = 0; u < 4; ++u) {
        short hs, ls; split1(ov[df][4*g+u]*inv, hs, ls);
        aph[ao + dbase + u] = hs;
        apl[ao + dbase + u] = ls;
      }
    }
  }
  if (h5 == 0) {
    const size_t base = ((size_t)(b*NH + h)*LSEQ + qi)*2;
    ml[base]   = m;
    ml[base+1] = lsum;
  }
}

// ---------------------------------------------------------------------------
extern "C" void kernel_launch(void* const* d_in, const int* in_sizes, int n_in,
                              void* d_out, int out_size, void* d_ws, size_t ws_size,
                              hipStream_t stream) {
  (void)in_sizes; (void)n_in; (void)out_size; (void)ws_size;
  const float* query     = (const float*)d_in[0];
  const float* in_proj_w = (const float*)d_in[3];
  const float* in_proj_b = (const float*)d_in[4];
  const float* s1        = (const float*)d_in[5];
  const float* sh1       = (const float*)d_in[6];
  const float* s2        = (const float*)d_in[7];
  const float* sh2       = (const float*)d_in[8];
  const float* out_w     = (const float*)d_in[9];
  const float* out_b     = (const float*)d_in[10];
  const float* l1_dw     = (const float*)d_in[11];
  const float* l1_db     = (const float*)d_in[12];
  const float* l1_uw     = (const float*)d_in[13];
  const float* l1_ub     = (const float*)d_in[14];
  const float* l1_s      = (const float*)d_in[15];
  const float* l2_dw     = (const float*)d_in[16];
  const float* l2_db     = (const float*)d_in[17];
  const float* l2_uw     = (const float*)d_in[18];
  const float* l2_ub     = (const float*)d_in[19];
  const float* l2_s      = (const float*)d_in[20];

  float* out2  = (float*)d_out;                      // (L,B,E)
  float* attnW = out2 + (size_t)LSEQ*BATCH*EMB;      // (B,L,L)

  // ---- workspace byte layout (~65.4 MB, aliased) ----
  char* ws = (char*)d_ws;
  short* W1H = (short*)(ws + 0);          // 2304*768
  short* W1L = (short*)(ws + 3538944);
  short* U1H = (short*)(ws + 7077888);    // 2304*64
  short* U1L = (short*)(ws + 7372800);
  short* WOH = (short*)(ws + 7667712);    // 768*768
  short* WOL = (short*)(ws + 8847360);
  short* WO2H= (short*)(ws + 10027008);
  short* WO2L= (short*)(ws + 11206656);
  short* U2H = (short*)(ws + 12386304);   // 768*64
  short* U2L = (short*)(ws + 12484608);
  short* QRH = (short*)(ws + 12582912);   // 4096*768 query planes | alias: ap
  short* QRL = (short*)(ws + 18874368);
  short* QPH = (short*)(ws + 25165824);   // [b][i][768] q planes
  short* QPL = (short*)(ws + 31457280);
  short* KPH = (short*)(ws + 37748736);   // [b][j][768] k planes | alias: o1p
  short* KPL = (short*)(ws + 44040192);
  short* VTH = (short*)(ws + 50331648);   // [b][h][d][j] vt | alias: out1 f32
  short* VTL = (short*)(ws + 56623104);
  short* T1H = (short*)(ws + 62914560);   // 4096*64
  short* T1L = (short*)(ws + 63438848);
  short* T2H = (short*)(ws + 63963136);
  short* T2L = (short*)(ws + 64487424);
  float* ML  = (float*)(ws + 65011712);   // (B,NH,L,2)
  short* APH = QRH;  short* APL = QRL;    // attn planes (query dead)
  short* O1PH= KPH;  short* O1PL= KPL;    // out1 planes (kp dead after attnw)
  float* OUT1F = (float*)(ws + 50331648); // out1 f32 (vt dead after flash)

  // 1) split query + all scale-folded weights into planes
  convert_all<<<dim3(3072), dim3(256), 0, stream>>>(
      query, in_proj_w, s1, l1_uw, l1_s, out_w, s2, l2_uw, l2_s,
      QRH, QRL, W1H, W1L, U1H, U1L, WOH, WOL, WO2H, WO2L, U2H, U2L);

  // 2) t1 = relu(query @ l1_dw^T + l1_db) -> planes
  gemm_lora<<<dim3(LB/32), dim3(256), 0, stream>>>(query, l1_dw, l1_db, T1H, T1L);

  // 3) qkv GEMM -> q/k planes + vt planes (scatter epilogue)
  gemm_p<2, true><<<dim3(32*18), dim3(256), 0, stream>>>(
      QRH, QRL, W1H, W1L, T1H, T1L, U1H, U1L,
      in_proj_b, s1, sh1, l1_ub, l1_s, 1,
      nullptr, nullptr, nullptr,
      QPH, QPL, KPH, KPL, VTH, VTL, E3, EMB, 32, 18);

  // 4) flash attention -> attn planes + (m,l)
  flash_p<<<dim3(LSEQ/128, BATCH, NH), dim3(256), 0, stream>>>(
      QPH, QPL, KPH, KPL, VTH, VTL, APH, APL, ML);

  // 5) attn_weights (mean over heads, write-once)
  attnw_p<<<dim3(256, 1, BATCH), dim3(256), 0, stream>>>(
      QPH, QPL, KPH, KPL, ML, attnW);

  // 6) out1 = attn @ out_w^T + out_b -> f32 + planes
  gemm_p<1, false><<<dim3(32*6), dim3(256), 0, stream>>>(
      APH, APL, WOH, WOL, nullptr, nullptr, nullptr, nullptr,
      out_b, nullptr, nullptr, nullptr, nullptr, 0,
      OUT1F, O1PH, O1PL,
      nullptr, nullptr, nullptr, nullptr, nullptr, nullptr, EMB, EMB, 32, 6);

  // 7) t2 = relu(out1 @ l2_dw^T + l2_db) -> planes
  gemm_lora<<<dim3(LB/32), dim3(256), 0, stream>>>(OUT1F, l2_dw, l2_db, T2H, T2L);

  // 8) out2 = ssf2(out1 @ out_w^T + out_b) + (t2 @ l2_uw^T + l2_ub)*l2_s
  gemm_p<0, true><<<dim3(32*6), dim3(256), 0, stream>>>(
      O1PH, O1PL, WO2H, WO2L, T2H, T2L, U2H, U2L,
      out_b, s2, sh2, l2_ub, l2_s, 0,
      out2, nullptr, nullptr,
      nullptr, nullptr, nullptr, nullptr, nullptr, nullptr, EMB, EMB, 32, 6);
}